// Round 1
// baseline (1430.593 us; speedup 1.0000x reference)
//
#include <hip/hip_runtime.h>
#include <math.h>

// MTGCN: 3x ChebConv(K=2) + 2 linears + link-pred loss on MI355X.
// Key algebraic rewrite: L_hat(x) @ W == L_hat(x @ W)  (both linear) ->
// propagate on the narrow side: conv1 before GEMM (128 dims), conv2/conv3 after
// (100 / 2 dims). All fp32 (no fp32 MFMA on CDNA4; threshold is absmax vs np f32).

#define BM 64
#define BN 64
#define BK 16

// ---------------- GEMM core: C-tile accumulate, A[M,K] row-major, B [K,N] or [N,K](TRANSB)
template<bool TRANSB>
__device__ __forceinline__ void gemm_accumulate(
    float acc[4][4],
    const float* __restrict__ A, int M, int K,
    const float* __restrict__ B, int N,
    int m0, int n0,
    float (*As)[BM + 4], float (*Bs)[BN])
{
  const int tid = threadIdx.y * 16 + threadIdx.x;
  const int nT = (K + BK - 1) / BK;
  for (int t = 0; t < nT; ++t) {
    const int k0 = t * BK;
    { // A tile 64x16, float4 along K (K%4==0 for all call sites)
      const int m = tid >> 2;
      const int k = (tid & 3) << 2;
      const int gm = m0 + m, gk = k0 + k;
      float4 v = make_float4(0.f, 0.f, 0.f, 0.f);
      if (gm < M && gk < K) v = *(const float4*)(A + (size_t)gm * K + gk);
      As[k + 0][m] = v.x; As[k + 1][m] = v.y; As[k + 2][m] = v.z; As[k + 3][m] = v.w;
    }
    if (TRANSB) { // B[N,K]: load float4 along K, transpose into Bs
      const int n = tid >> 2;
      const int k = (tid & 3) << 2;
      const int gn = n0 + n, gk = k0 + k;
      float4 v = make_float4(0.f, 0.f, 0.f, 0.f);
      if (gn < N && gk < K) v = *(const float4*)(B + (size_t)gn * K + gk);
      Bs[k + 0][n] = v.x; Bs[k + 1][n] = v.y; Bs[k + 2][n] = v.z; Bs[k + 3][n] = v.w;
    } else {      // B[K,N]: float4 along N, coalesced, vector LDS store
      const int n = (tid & 15) << 2;
      const int k = tid >> 4;
      const int gn = n0 + n, gk = k0 + k;
      float4 v = make_float4(0.f, 0.f, 0.f, 0.f);
      if (gn < N && gk < K) v = *(const float4*)(B + (size_t)gk * N + gn);
      *(float4*)&Bs[k][n] = v;
    }
    __syncthreads();
#pragma unroll
    for (int kk = 0; kk < BK; ++kk) {
      float a[4], b[4];
      *(float4*)a = *(const float4*)&As[kk][threadIdx.y << 2];
      *(float4*)b = *(const float4*)&Bs[kk][threadIdx.x << 2];
#pragma unroll
      for (int i = 0; i < 4; ++i)
#pragma unroll
        for (int j = 0; j < 4; ++j)
          acc[i][j] = fmaf(a[i], b[j], acc[i][j]);
    }
    __syncthreads();
  }
}

// ---------------- conv1: h = relu(x0@W1[0] + tx0@W1[1] + b1), K=128, N=300
__global__ __launch_bounds__(256) void gemm_conv1(
    const float* __restrict__ x0, const float* __restrict__ tx0,
    const float* __restrict__ W1, const float* __restrict__ b1,
    float* __restrict__ h, int M)
{
  __shared__ float As[BK][BM + 4];
  __shared__ float Bs[BK][BN];
  float acc[4][4] = {};
  const int m0 = blockIdx.y * BM, n0 = blockIdx.x * BN;
  gemm_accumulate<false>(acc, x0,  M, 128, W1,             300, m0, n0, As, Bs);
  gemm_accumulate<false>(acc, tx0, M, 128, W1 + 128 * 300, 300, m0, n0, As, Bs);
  const int rb = m0 + (threadIdx.y << 2), cb = n0 + (threadIdx.x << 2);
#pragma unroll
  for (int i = 0; i < 4; ++i) {
    const int gm = rb + i; if (gm >= M) break;
#pragma unroll
    for (int j = 0; j < 4; ++j) {
      const int gn = cb + j; if (gn >= 300) continue;
      h[(size_t)gm * 300 + gn] = fmaxf(acc[i][j] + b1[gn], 0.f);
    }
  }
}

// ---------------- conv2 pre: z=0: Ar = h@W2[0]+b2 ; z=1: Br = h@W2[1]. K=300, N=100
__global__ __launch_bounds__(256) void gemm_conv2(
    const float* __restrict__ hh, const float* __restrict__ W2,
    const float* __restrict__ b2, float* __restrict__ Ar, float* __restrict__ Br, int M)
{
  __shared__ float As[BK][BM + 4];
  __shared__ float Bs[BK][BN];
  float acc[4][4] = {};
  const int zi = blockIdx.z;
  const float* B = W2 + (size_t)zi * 300 * 100;
  float* C = zi ? Br : Ar;
  const int m0 = blockIdx.y * BM, n0 = blockIdx.x * BN;
  gemm_accumulate<false>(acc, hh, M, 300, B, 100, m0, n0, As, Bs);
  const int rb = m0 + (threadIdx.y << 2), cb = n0 + (threadIdx.x << 2);
#pragma unroll
  for (int i = 0; i < 4; ++i) {
    const int gm = rb + i; if (gm >= M) break;
#pragma unroll
    for (int j = 0; j < 4; ++j) {
      const int gn = cb + j; if (gn >= 100) continue;
      C[(size_t)gm * 100 + gn] = acc[i][j] + (zi ? 0.f : b2[gn]);
    }
  }
}

// ---------------- lins: z=0: x2 = x1 + relu(x0@lin1W^T + lin1b); z=1: z = x1 + relu(x0@lin2W^T + lin2b)
__global__ __launch_bounds__(256) void gemm_lin(
    const float* __restrict__ x0,
    const float* __restrict__ l1W, const float* __restrict__ l1b,
    const float* __restrict__ l2W, const float* __restrict__ l2b,
    const float* __restrict__ x1, float* __restrict__ x2, float* __restrict__ zz, int M)
{
  __shared__ float As[BK][BM + 4];
  __shared__ float Bs[BK][BN];
  float acc[4][4] = {};
  const int zi = blockIdx.z;
  const float* B    = zi ? l2W : l1W;
  const float* bias = zi ? l2b : l1b;
  float* C          = zi ? zz  : x2;
  const int m0 = blockIdx.y * BM, n0 = blockIdx.x * BN;
  gemm_accumulate<true>(acc, x0, M, 128, B, 100, m0, n0, As, Bs);
  const int rb = m0 + (threadIdx.y << 2), cb = n0 + (threadIdx.x << 2);
#pragma unroll
  for (int i = 0; i < 4; ++i) {
    const int gm = rb + i; if (gm >= M) break;
#pragma unroll
    for (int j = 0; j < 4; ++j) {
      const int gn = cb + j; if (gn >= 100) continue;
      const size_t idx = (size_t)gm * 100 + gn;
      C[idx] = x1[idx] + fmaxf(acc[i][j] + bias[gn], 0.f);
    }
  }
}

// ---------------- degree / dinv
__global__ void deg_kernel(const int* __restrict__ src, float* __restrict__ deg, int E) {
  const int e = blockIdx.x * blockDim.x + threadIdx.x;
  if (e < E) atomicAdd(deg + src[e], 1.0f);
}
__global__ void dinv_kernel(float* __restrict__ d, int n) {
  const int i = blockIdx.x * blockDim.x + threadIdx.x;
  if (i < n) { const float v = d[i]; d[i] = (v > 0.f) ? 1.f / sqrtf(v) : 0.f; }
}

// ---------------- scatter: xout[dst] += (-dinv[src]*dinv[dst]) * xin[src], F features
template<int F>
__global__ void scatter_kernel(const float* __restrict__ xin, float* __restrict__ xout,
                               const int* __restrict__ src, const int* __restrict__ dst,
                               const float* __restrict__ dinv, int E)
{
  const long long idx = (long long)blockIdx.x * blockDim.x + threadIdx.x;
  if (idx >= (long long)E * F) return;
  const int e = (int)(idx / F);
  const int f = (int)(idx - (long long)e * F);
  const int s = src[e], d = dst[e];
  const float w = -dinv[s] * dinv[d];
  atomicAdd(xout + (size_t)d * F + f, w * xin[(size_t)s * F + f]);
}

// ---------------- x1 = relu(Ar + tx) in place over Ar
__global__ void x1_kernel(float* __restrict__ a, const float* __restrict__ tx, int n) {
  const int i = blockIdx.x * blockDim.x + threadIdx.x;
  if (i < n) a[i] = fmaxf(a[i] + tx[i], 0.f);
}

// ---------------- conv3 GEMMs: t0 = x2@W3[0]+b3, t1 = x2@W3[1]. K=100, N=2, thread/row
__global__ __launch_bounds__(256) void w3_kernel(
    const float* __restrict__ x2, const float* __restrict__ W3,
    const float* __restrict__ b3, float* __restrict__ t0, float* __restrict__ t1, int M)
{
  __shared__ float w[400];
  for (int i = threadIdx.x; i < 400; i += 256) w[i] = W3[i];
  __syncthreads();
  const int m = blockIdx.x * 256 + threadIdx.x;
  if (m >= M) return;
  const float4* row = (const float4*)(x2 + (size_t)m * 100);
  float a0 = 0.f, a1 = 0.f, c0 = 0.f, c1v = 0.f;
#pragma unroll
  for (int q = 0; q < 25; ++q) {
    const float4 v = row[q];
    const int k2 = q * 8; // = 2*k
    a0  = fmaf(v.x, w[k2 + 0], a0);  a1  = fmaf(v.x, w[k2 + 1], a1);
    a0  = fmaf(v.y, w[k2 + 2], a0);  a1  = fmaf(v.y, w[k2 + 3], a1);
    a0  = fmaf(v.z, w[k2 + 4], a0);  a1  = fmaf(v.z, w[k2 + 5], a1);
    a0  = fmaf(v.w, w[k2 + 6], a0);  a1  = fmaf(v.w, w[k2 + 7], a1);
    c0  = fmaf(v.x, w[200 + k2 + 0], c0);  c1v = fmaf(v.x, w[200 + k2 + 1], c1v);
    c0  = fmaf(v.y, w[200 + k2 + 2], c0);  c1v = fmaf(v.y, w[200 + k2 + 3], c1v);
    c0  = fmaf(v.z, w[200 + k2 + 4], c0);  c1v = fmaf(v.z, w[200 + k2 + 5], c1v);
    c0  = fmaf(v.w, w[200 + k2 + 6], c0);  c1v = fmaf(v.w, w[200 + k2 + 7], c1v);
  }
  t0[(size_t)m * 2 + 0] = a0 + b3[0];
  t0[(size_t)m * 2 + 1] = a1 + b3[1];
  t1[(size_t)m * 2 + 0] = c0;
  t1[(size_t)m * 2 + 1] = c1v;
}

// ---------------- link-pred loss terms: sum_p log(sigmoid(s)+1e-15) or log(1-sigmoid(s)+1e-15)
__global__ void loss_kernel(const float* __restrict__ z, const int* __restrict__ ia,
                            const int* __restrict__ ib, int P, int neg, float* __restrict__ acc)
{
  const int p = blockIdx.x * blockDim.x + threadIdx.x;
  float term = 0.f;
  if (p < P) {
    const float4* za = (const float4*)(z + (size_t)ia[p] * 100);
    const float4* zb = (const float4*)(z + (size_t)ib[p] * 100);
    float s = 0.f;
#pragma unroll
    for (int q = 0; q < 25; ++q) {
      const float4 a = za[q], b = zb[q];
      s += a.x * b.x + a.y * b.y + a.z * b.z + a.w * b.w;
    }
    // mimic JAX f32 semantics: f32 sigmoid, +1e-15f, logf
    const float sig = 1.f / (1.f + expf(-s));
    term = neg ? logf(1.f - sig + 1e-15f) : logf(sig + 1e-15f);
  }
#pragma unroll
  for (int off = 32; off > 0; off >>= 1) term += __shfl_down(term, off, 64);
  if ((threadIdx.x & 63) == 0) atomicAdd(acc + neg, term);
}

// ---------------- final: out = t0 + tx3 (+scalars)
__global__ void final_kernel(const float* __restrict__ t0, const float* __restrict__ tx3,
                             const float* __restrict__ accs, const float* __restrict__ c1,
                             const float* __restrict__ c2, float* __restrict__ out,
                             int M, float invP)
{
  const int i = blockIdx.x * blockDim.x + threadIdx.x;
  if (i < 2 * M) out[i] = t0[i] + tx3[i];
  if (i == 0) {
    out[2 * M + 0] = -(accs[0] + accs[1]) * invP; // pos_loss + neg_loss
    out[2 * M + 1] = c1[0];
    out[2 * M + 2] = c2[0];
  }
}

extern "C" void kernel_launch(void* const* d_in, const int* in_sizes, int n_in,
                              void* d_out, int out_size, void* d_ws, size_t ws_size,
                              hipStream_t stream)
{
  const float* x   = (const float*)d_in[0];
  const int*   ei  = (const int*)d_in[1];
  const int*   ep  = (const int*)d_in[2];
  const int*   en  = (const int*)d_in[3];
  const float* W1  = (const float*)d_in[4];
  const float* b1  = (const float*)d_in[5];
  const float* W2  = (const float*)d_in[6];
  const float* b2  = (const float*)d_in[7];
  const float* W3  = (const float*)d_in[8];
  const float* b3  = (const float*)d_in[9];
  const float* l1W = (const float*)d_in[10];
  const float* l1b = (const float*)d_in[11];
  const float* l2W = (const float*)d_in[12];
  const float* l2b = (const float*)d_in[13];
  const float* c1  = (const float*)d_in[14];
  const float* c2  = (const float*)d_in[15];
  float* out = (float*)d_out;

  const int M = in_sizes[0] / 128;  // 50000 nodes
  const int E = in_sizes[1] / 2;    // 800000 edges
  const int P = in_sizes[2] / 2;    // 400000 pairs
  const int* src = ei;
  const int* dst = ei + E;

  // workspace layout (floats), all offsets 16B-aligned
  float* ws = (float*)d_ws;
  size_t o = 0;
  float* dinv = ws + o; o += 50176;
  float* tx0  = ws + o; o += (size_t)M * 128;  // L_hat x0
  float* h    = ws + o; o += (size_t)M * 300;  // conv1 out
  float* Ar   = ws + o; o += (size_t)M * 100;  // h@W2[0]+b2 -> x1 (in place)
  float* Br   = ws + o; o += (size_t)M * 100;  // h@W2[1]    -> z  (reused)
  float* txb  = ws + o; o += (size_t)M * 100;  // L_hat(Br)  -> x2 (reused)
  float* t0   = ws + o; o += (size_t)M * 2;
  float* t1   = ws + o; o += (size_t)M * 2;
  float* tx3  = ws + o; o += (size_t)M * 2;
  float* accs = ws + o; o += 8;

  hipMemsetAsync(dinv, 0, (size_t)M * 4, stream);
  hipMemsetAsync(tx0,  0, (size_t)M * 128 * 4, stream);
  hipMemsetAsync(txb,  0, (size_t)M * 100 * 4, stream);
  hipMemsetAsync(tx3,  0, (size_t)M * 2 * 4, stream);
  hipMemsetAsync(accs, 0, 2 * 4, stream);

  deg_kernel<<<(E + 255) / 256, 256, 0, stream>>>(src, dinv, E);
  dinv_kernel<<<(M + 255) / 256, 256, 0, stream>>>(dinv, M);

  { const long long tot = (long long)E * 128;
    scatter_kernel<128><<<(int)((tot + 255) / 256), 256, 0, stream>>>(x, tx0, src, dst, dinv, E); }

  gemm_conv1<<<dim3((300 + BN - 1) / BN, (M + BM - 1) / BM), dim3(16, 16), 0, stream>>>(
      x, tx0, W1, b1, h, M);

  gemm_conv2<<<dim3((100 + BN - 1) / BN, (M + BM - 1) / BM, 2), dim3(16, 16), 0, stream>>>(
      h, W2, b2, Ar, Br, M);

  { const long long tot = (long long)E * 100;
    scatter_kernel<100><<<(int)((tot + 255) / 256), 256, 0, stream>>>(Br, txb, src, dst, dinv, E); }

  x1_kernel<<<(M * 100 + 255) / 256, 256, 0, stream>>>(Ar, txb, M * 100);

  gemm_lin<<<dim3((100 + BN - 1) / BN, (M + BM - 1) / BM, 2), dim3(16, 16), 0, stream>>>(
      x, l1W, l1b, l2W, l2b, Ar /*x1*/, txb /*x2*/, Br /*z*/, M);

  loss_kernel<<<(P + 255) / 256, 256, 0, stream>>>(Br, ep, ep + P, P, 0, accs);
  loss_kernel<<<(P + 255) / 256, 256, 0, stream>>>(Br, en, en + P, P, 1, accs);

  w3_kernel<<<(M + 255) / 256, 256, 0, stream>>>(txb /*x2*/, W3, b3, t0, t1, M);

  { const long long tot = (long long)E * 2;
    scatter_kernel<2><<<(int)((tot + 255) / 256), 256, 0, stream>>>(t1, tx3, src, dst, dinv, E); }

  final_kernel<<<(2 * M + 255) / 256, 256, 0, stream>>>(t0, tx3, accs, c1, c2, out, M, 1.0f / (float)P);
}

// Round 2
// 956.065 us; speedup vs baseline: 1.4963x; 1.4963x over previous
//
#include <hip/hip_runtime.h>
#include <math.h>

// MTGCN: 3x ChebConv(K=2) + 2 linears + link-pred loss on MI355X.
// R1: replace atomic scatters with CSR-gather (build dst-CSR once per call,
// reuse for all three propagations); wave-per-pair coalesced loss.
// Propagate on the narrow side: conv1 before GEMM (128), conv2/conv3 after (100/2).

#define BM 64
#define BN 64
#define BK 16

// ---------------- GEMM core: C-tile accumulate, A[M,K] row-major, B [K,N] or [N,K](TRANSB)
template<bool TRANSB>
__device__ __forceinline__ void gemm_accumulate(
    float acc[4][4],
    const float* __restrict__ A, int M, int K,
    const float* __restrict__ B, int N,
    int m0, int n0,
    float (*As)[BM + 4], float (*Bs)[BN])
{
  const int tid = threadIdx.y * 16 + threadIdx.x;
  const int nT = (K + BK - 1) / BK;
  for (int t = 0; t < nT; ++t) {
    const int k0 = t * BK;
    { // A tile 64x16, float4 along K
      const int m = tid >> 2;
      const int k = (tid & 3) << 2;
      const int gm = m0 + m, gk = k0 + k;
      float4 v = make_float4(0.f, 0.f, 0.f, 0.f);
      if (gm < M && gk < K) v = *(const float4*)(A + (size_t)gm * K + gk);
      As[k + 0][m] = v.x; As[k + 1][m] = v.y; As[k + 2][m] = v.z; As[k + 3][m] = v.w;
    }
    if (TRANSB) { // B[N,K]: float4 along K, transpose into Bs
      const int n = tid >> 2;
      const int k = (tid & 3) << 2;
      const int gn = n0 + n, gk = k0 + k;
      float4 v = make_float4(0.f, 0.f, 0.f, 0.f);
      if (gn < N && gk < K) v = *(const float4*)(B + (size_t)gn * K + gk);
      Bs[k + 0][n] = v.x; Bs[k + 1][n] = v.y; Bs[k + 2][n] = v.z; Bs[k + 3][n] = v.w;
    } else {      // B[K,N]: float4 along N, coalesced
      const int n = (tid & 15) << 2;
      const int k = tid >> 4;
      const int gn = n0 + n, gk = k0 + k;
      float4 v = make_float4(0.f, 0.f, 0.f, 0.f);
      if (gn < N && gk < K) v = *(const float4*)(B + (size_t)gk * N + gn);
      *(float4*)&Bs[k][n] = v;
    }
    __syncthreads();
#pragma unroll
    for (int kk = 0; kk < BK; ++kk) {
      float a[4], b[4];
      *(float4*)a = *(const float4*)&As[kk][threadIdx.y << 2];
      *(float4*)b = *(const float4*)&Bs[kk][threadIdx.x << 2];
#pragma unroll
      for (int i = 0; i < 4; ++i)
#pragma unroll
        for (int j = 0; j < 4; ++j)
          acc[i][j] = fmaf(a[i], b[j], acc[i][j]);
    }
    __syncthreads();
  }
}

// ---------------- conv1: h = relu(x0@W1[0] + tx0@W1[1] + b1), K=128, N=300
__global__ __launch_bounds__(256) void gemm_conv1(
    const float* __restrict__ x0, const float* __restrict__ tx0,
    const float* __restrict__ W1, const float* __restrict__ b1,
    float* __restrict__ h, int M)
{
  __shared__ float As[BK][BM + 4];
  __shared__ float Bs[BK][BN];
  float acc[4][4] = {};
  const int m0 = blockIdx.y * BM, n0 = blockIdx.x * BN;
  gemm_accumulate<false>(acc, x0,  M, 128, W1,             300, m0, n0, As, Bs);
  gemm_accumulate<false>(acc, tx0, M, 128, W1 + 128 * 300, 300, m0, n0, As, Bs);
  const int rb = m0 + (threadIdx.y << 2), cb = n0 + (threadIdx.x << 2);
#pragma unroll
  for (int i = 0; i < 4; ++i) {
    const int gm = rb + i; if (gm >= M) break;
#pragma unroll
    for (int j = 0; j < 4; ++j) {
      const int gn = cb + j; if (gn >= 300) continue;
      h[(size_t)gm * 300 + gn] = fmaxf(acc[i][j] + b1[gn], 0.f);
    }
  }
}

// ---------------- conv2 pre: z=0: Ar = h@W2[0]+b2 ; z=1: Br = h@W2[1]. K=300, N=100
__global__ __launch_bounds__(256) void gemm_conv2(
    const float* __restrict__ hh, const float* __restrict__ W2,
    const float* __restrict__ b2, float* __restrict__ Ar, float* __restrict__ Br, int M)
{
  __shared__ float As[BK][BM + 4];
  __shared__ float Bs[BK][BN];
  float acc[4][4] = {};
  const int zi = blockIdx.z;
  const float* B = W2 + (size_t)zi * 300 * 100;
  float* C = zi ? Br : Ar;
  const int m0 = blockIdx.y * BM, n0 = blockIdx.x * BN;
  gemm_accumulate<false>(acc, hh, M, 300, B, 100, m0, n0, As, Bs);
  const int rb = m0 + (threadIdx.y << 2), cb = n0 + (threadIdx.x << 2);
#pragma unroll
  for (int i = 0; i < 4; ++i) {
    const int gm = rb + i; if (gm >= M) break;
#pragma unroll
    for (int j = 0; j < 4; ++j) {
      const int gn = cb + j; if (gn >= 100) continue;
      C[(size_t)gm * 100 + gn] = acc[i][j] + (zi ? 0.f : b2[gn]);
    }
  }
}

// ---------------- lins: z=0: x2 = x1 + relu(x0@lin1W^T+b); z=1: z = x1 + relu(x0@lin2W^T+b)
__global__ __launch_bounds__(256) void gemm_lin(
    const float* __restrict__ x0,
    const float* __restrict__ l1W, const float* __restrict__ l1b,
    const float* __restrict__ l2W, const float* __restrict__ l2b,
    const float* __restrict__ x1, float* __restrict__ x2, float* __restrict__ zz, int M)
{
  __shared__ float As[BK][BM + 4];
  __shared__ float Bs[BK][BN];
  float acc[4][4] = {};
  const int zi = blockIdx.z;
  const float* B    = zi ? l2W : l1W;
  const float* bias = zi ? l2b : l1b;
  float* C          = zi ? zz  : x2;
  const int m0 = blockIdx.y * BM, n0 = blockIdx.x * BN;
  gemm_accumulate<true>(acc, x0, M, 128, B, 100, m0, n0, As, Bs);
  const int rb = m0 + (threadIdx.y << 2), cb = n0 + (threadIdx.x << 2);
#pragma unroll
  for (int i = 0; i < 4; ++i) {
    const int gm = rb + i; if (gm >= M) break;
#pragma unroll
    for (int j = 0; j < 4; ++j) {
      const int gn = cb + j; if (gn >= 100) continue;
      const size_t idx = (size_t)gm * 100 + gn;
      C[idx] = x1[idx] + fmaxf(acc[i][j] + bias[gn], 0.f);
    }
  }
}

// ---------------- degree (src, float) + in-count (dst, int), fused single pass
__global__ void deg_count_kernel(const int* __restrict__ src, const int* __restrict__ dst,
                                 float* __restrict__ deg, int* __restrict__ cnt, int E)
{
  const int e = blockIdx.x * blockDim.x + threadIdx.x;
  if (e < E) { atomicAdd(deg + src[e], 1.0f); atomicAdd(cnt + dst[e], 1); }
}
__global__ void dinv_kernel(float* __restrict__ d, int n) {
  const int i = blockIdx.x * blockDim.x + threadIdx.x;
  if (i < n) { const float v = d[i]; d[i] = (v > 0.f) ? 1.f / sqrtf(v) : 0.f; }
}

// ---------------- CSR build: 3-kernel exclusive scan of cnt -> ptr, then fill
__global__ void scan_local(const int* __restrict__ cnt, int* __restrict__ ptr,
                           int* __restrict__ bsum, int n)
{
  __shared__ int tmp[256];
  const int i = blockIdx.x * 256 + threadIdx.x;
  const int v = (i < n) ? cnt[i] : 0;
  tmp[threadIdx.x] = v;
  __syncthreads();
  for (int off = 1; off < 256; off <<= 1) {
    const int t = (threadIdx.x >= off) ? tmp[threadIdx.x - off] : 0;
    __syncthreads();
    tmp[threadIdx.x] += t;
    __syncthreads();
  }
  if (i < n) ptr[i] = tmp[threadIdx.x] - v;            // local exclusive
  if (threadIdx.x == 255) bsum[blockIdx.x] = tmp[255]; // block total
}
__global__ void scan_bsum(int* __restrict__ bsum, int nb) { // single block, nb<=256
  __shared__ int tmp[256];
  const int v = (threadIdx.x < nb) ? bsum[threadIdx.x] : 0;
  tmp[threadIdx.x] = v;
  __syncthreads();
  for (int off = 1; off < 256; off <<= 1) {
    const int t = (threadIdx.x >= off) ? tmp[threadIdx.x - off] : 0;
    __syncthreads();
    tmp[threadIdx.x] += t;
    __syncthreads();
  }
  if (threadIdx.x < nb) bsum[threadIdx.x] = tmp[threadIdx.x] - v; // exclusive
}
__global__ void scan_add(int* __restrict__ ptr, const int* __restrict__ bsum, int n, int E) {
  const int i = blockIdx.x * 256 + threadIdx.x;
  if (i < n) ptr[i] += bsum[blockIdx.x];
  if (i == 0) ptr[n] = E;
}
__global__ void fill_csr(const int* __restrict__ src, const int* __restrict__ dst,
                         const float* __restrict__ dinv, int* __restrict__ cur,
                         int* __restrict__ cs, float* __restrict__ cw, int E)
{
  const int e = blockIdx.x * blockDim.x + threadIdx.x;
  if (e >= E) return;
  const int s = src[e], d = dst[e];
  const int pos = atomicAdd(cur + d, 1);
  cs[pos] = s;
  cw[pos] = -dinv[s] * dinv[d];
}

// ---------------- gathers: one wave per dst node, coalesced row reads, no atomics
__global__ __launch_bounds__(256) void gather128(
    const float* __restrict__ xin, float* __restrict__ xout,
    const int* __restrict__ ptr, const int* __restrict__ cs,
    const float* __restrict__ cw, int M)
{
  const int node = (blockIdx.x * 256 + threadIdx.x) >> 6;
  const int lane = threadIdx.x & 63;
  if (node >= M) return;
  const int beg = ptr[node], end = ptr[node + 1];
  float a0 = 0.f, a1 = 0.f;
  for (int p = beg; p < end; ++p) {
    const int s = cs[p]; const float w = cw[p];
    const float2 v = *(const float2*)(xin + (size_t)s * 128 + 2 * lane);
    a0 = fmaf(w, v.x, a0); a1 = fmaf(w, v.y, a1);
  }
  *(float2*)(xout + (size_t)node * 128 + 2 * lane) = make_float2(a0, a1);
}
__global__ __launch_bounds__(256) void gather100(
    const float* __restrict__ xin, float* __restrict__ xout,
    const int* __restrict__ ptr, const int* __restrict__ cs,
    const float* __restrict__ cw, int M)
{
  const int node = (blockIdx.x * 256 + threadIdx.x) >> 6;
  const int lane = threadIdx.x & 63;
  if (node >= M) return;
  const int beg = ptr[node], end = ptr[node + 1];
  float a0 = 0.f, a1 = 0.f;
  for (int p = beg; p < end; ++p) {
    const int s = cs[p]; const float w = cw[p];
    if (lane < 50) {
      const float2 v = *(const float2*)(xin + (size_t)s * 100 + 2 * lane);
      a0 = fmaf(w, v.x, a0); a1 = fmaf(w, v.y, a1);
    }
  }
  if (lane < 50)
    *(float2*)(xout + (size_t)node * 100 + 2 * lane) = make_float2(a0, a1);
}
__global__ void gather2(
    const float* __restrict__ xin, float* __restrict__ xout,
    const int* __restrict__ ptr, const int* __restrict__ cs,
    const float* __restrict__ cw, int M)
{
  const int i = blockIdx.x * blockDim.x + threadIdx.x;
  if (i >= M) return;
  float a0 = 0.f, a1 = 0.f;
  const int beg = ptr[i], end = ptr[i + 1];
  for (int p = beg; p < end; ++p) {
    const int s = cs[p]; const float w = cw[p];
    const float2 v = *(const float2*)(xin + (size_t)s * 2);
    a0 = fmaf(w, v.x, a0); a1 = fmaf(w, v.y, a1);
  }
  *(float2*)(xout + (size_t)i * 2) = make_float2(a0, a1);
}

// ---------------- x1 = relu(Ar + tx) in place
__global__ void x1_kernel(float* __restrict__ a, const float* __restrict__ tx, int n) {
  const int i = blockIdx.x * blockDim.x + threadIdx.x;
  if (i < n) a[i] = fmaxf(a[i] + tx[i], 0.f);
}

// ---------------- conv3 GEMMs: t0 = x2@W3[0]+b3, t1 = x2@W3[1]
__global__ __launch_bounds__(256) void w3_kernel(
    const float* __restrict__ x2, const float* __restrict__ W3,
    const float* __restrict__ b3, float* __restrict__ t0, float* __restrict__ t1, int M)
{
  __shared__ float w[400];
  for (int i = threadIdx.x; i < 400; i += 256) w[i] = W3[i];
  __syncthreads();
  const int m = blockIdx.x * 256 + threadIdx.x;
  if (m >= M) return;
  const float4* row = (const float4*)(x2 + (size_t)m * 100);
  float a0 = 0.f, a1 = 0.f, c0 = 0.f, c1v = 0.f;
#pragma unroll
  for (int q = 0; q < 25; ++q) {
    const float4 v = row[q];
    const int k2 = q * 8;
    a0  = fmaf(v.x, w[k2 + 0], a0);  a1  = fmaf(v.x, w[k2 + 1], a1);
    a0  = fmaf(v.y, w[k2 + 2], a0);  a1  = fmaf(v.y, w[k2 + 3], a1);
    a0  = fmaf(v.z, w[k2 + 4], a0);  a1  = fmaf(v.z, w[k2 + 5], a1);
    a0  = fmaf(v.w, w[k2 + 6], a0);  a1  = fmaf(v.w, w[k2 + 7], a1);
    c0  = fmaf(v.x, w[200 + k2 + 0], c0);  c1v = fmaf(v.x, w[200 + k2 + 1], c1v);
    c0  = fmaf(v.y, w[200 + k2 + 2], c0);  c1v = fmaf(v.y, w[200 + k2 + 3], c1v);
    c0  = fmaf(v.z, w[200 + k2 + 4], c0);  c1v = fmaf(v.z, w[200 + k2 + 5], c1v);
    c0  = fmaf(v.w, w[200 + k2 + 6], c0);  c1v = fmaf(v.w, w[200 + k2 + 7], c1v);
  }
  t0[(size_t)m * 2 + 0] = a0 + b3[0];
  t0[(size_t)m * 2 + 1] = a1 + b3[1];
  t1[(size_t)m * 2 + 0] = c0;
  t1[(size_t)m * 2 + 1] = c1v;
}

// ---------------- fused loss: wave per pair (coalesced 400B row reads), grid-stride,
// block-level LDS reduce, 2 atomics per block.
__global__ __launch_bounds__(256) void loss_fused(
    const float* __restrict__ z, const int* __restrict__ ep,
    const int* __restrict__ en, int P, float* __restrict__ acc)
{
  __shared__ float red[8];
  const int lane = threadIdx.x & 63;
  const int wib  = threadIdx.x >> 6;
  const int gw   = blockIdx.x * 4 + wib;
  const int nw   = gridDim.x * 4;
  float tp = 0.f, tn = 0.f;
  for (int g = gw; g < 2 * P; g += nw) {
    const int neg = (g >= P);
    const int p = neg ? g - P : g;
    const int* ia = neg ? en : ep;
    const int na = ia[p], nb = ia[P + p];
    float s = 0.f;
    if (lane < 50) {
      const float2 a = *(const float2*)(z + (size_t)na * 100 + 2 * lane);
      const float2 b = *(const float2*)(z + (size_t)nb * 100 + 2 * lane);
      s = a.x * b.x + a.y * b.y;
    }
#pragma unroll
    for (int off = 32; off; off >>= 1) s += __shfl_down(s, off, 64);
    if (lane == 0) {
      const float sig = 1.f / (1.f + expf(-s));   // JAX f32 semantics
      if (neg) tn += logf(1.f - sig + 1e-15f);
      else     tp += logf(sig + 1e-15f);
    }
  }
  if (lane == 0) { red[wib] = tp; red[4 + wib] = tn; }
  __syncthreads();
  if (threadIdx.x == 0) {
    atomicAdd(acc + 0, red[0] + red[1] + red[2] + red[3]);
    atomicAdd(acc + 1, red[4] + red[5] + red[6] + red[7]);
  }
}

// ---------------- final: out = t0 + tx3 (+loss, scalars)
__global__ void final_kernel(const float* __restrict__ t0, const float* __restrict__ tx3,
                             const float* __restrict__ accs, const float* __restrict__ c1,
                             const float* __restrict__ c2, float* __restrict__ out,
                             int M, float invP)
{
  const int i = blockIdx.x * blockDim.x + threadIdx.x;
  if (i < 2 * M) out[i] = t0[i] + tx3[i];
  if (i == 0) {
    out[2 * M + 0] = -(accs[0] + accs[1]) * invP;
    out[2 * M + 1] = c1[0];
    out[2 * M + 2] = c2[0];
  }
}

extern "C" void kernel_launch(void* const* d_in, const int* in_sizes, int n_in,
                              void* d_out, int out_size, void* d_ws, size_t ws_size,
                              hipStream_t stream)
{
  const float* x   = (const float*)d_in[0];
  const int*   ei  = (const int*)d_in[1];
  const int*   ep  = (const int*)d_in[2];
  const int*   en  = (const int*)d_in[3];
  const float* W1  = (const float*)d_in[4];
  const float* b1  = (const float*)d_in[5];
  const float* W2  = (const float*)d_in[6];
  const float* b2  = (const float*)d_in[7];
  const float* W3  = (const float*)d_in[8];
  const float* b3  = (const float*)d_in[9];
  const float* l1W = (const float*)d_in[10];
  const float* l1b = (const float*)d_in[11];
  const float* l2W = (const float*)d_in[12];
  const float* l2b = (const float*)d_in[13];
  const float* c1  = (const float*)d_in[14];
  const float* c2  = (const float*)d_in[15];
  float* out = (float*)d_out;

  const int M = in_sizes[0] / 128;  // 50000
  const int E = in_sizes[1] / 2;    // 800000
  const int P = in_sizes[2] / 2;    // 400000
  const int* src = ei;
  const int* dst = ei + E;
  const int nb_scan = (M + 255) / 256; // 196 <= 256

  // workspace layout (4B units, 16B-aligned chunks)
  float* ws = (float*)d_ws;
  size_t o = 0;
  float* dinv = ws + o; o += 50176;
  int*   cnt  = (int*)(ws + o); o += (size_t)M;
  int*   ptr  = (int*)(ws + o); o += (size_t)M + 8;
  int*   cur  = (int*)(ws + o); o += (size_t)M;
  int*   bsum = (int*)(ws + o); o += 256;
  int*   csr_s = (int*)(ws + o);  o += (size_t)E;
  float* csr_w = ws + o;          o += (size_t)E;
  float* tx0  = ws + o; o += (size_t)M * 128;
  float* h    = ws + o; o += (size_t)M * 300;
  float* Ar   = ws + o; o += (size_t)M * 100;  // -> x1 (in place)
  float* Br   = ws + o; o += (size_t)M * 100;  // -> z
  float* txb  = ws + o; o += (size_t)M * 100;  // -> x2
  float* t0   = ws + o; o += (size_t)M * 2;
  float* t1   = ws + o; o += (size_t)M * 2;
  float* tx3  = ws + o; o += (size_t)M * 2;
  float* accs = ws + o; o += 8;

  hipMemsetAsync(dinv, 0, (size_t)M * 4, stream);
  hipMemsetAsync(cnt,  0, (size_t)M * 4, stream);
  hipMemsetAsync(accs, 0, 2 * 4, stream);

  // --- CSR build
  deg_count_kernel<<<(E + 255) / 256, 256, 0, stream>>>(src, dst, dinv, cnt, E);
  dinv_kernel<<<(M + 255) / 256, 256, 0, stream>>>(dinv, M);
  scan_local<<<nb_scan, 256, 0, stream>>>(cnt, ptr, bsum, M);
  scan_bsum<<<1, 256, 0, stream>>>(bsum, nb_scan);
  scan_add<<<nb_scan, 256, 0, stream>>>(ptr, bsum, M, E);
  hipMemcpyAsync(cur, ptr, (size_t)M * 4, hipMemcpyDeviceToDevice, stream);
  fill_csr<<<(E + 255) / 256, 256, 0, stream>>>(src, dst, dinv, cur, csr_s, csr_w, E);

  // --- conv1
  gather128<<<(M * 64 + 255) / 256, 256, 0, stream>>>(x, tx0, ptr, csr_s, csr_w, M);
  gemm_conv1<<<dim3((300 + BN - 1) / BN, (M + BM - 1) / BM), dim3(16, 16), 0, stream>>>(
      x, tx0, W1, b1, h, M);

  // --- conv2 (propagate after GEMM: 100 dims instead of 300)
  gemm_conv2<<<dim3((100 + BN - 1) / BN, (M + BM - 1) / BM, 2), dim3(16, 16), 0, stream>>>(
      h, W2, b2, Ar, Br, M);
  gather100<<<(M * 64 + 255) / 256, 256, 0, stream>>>(Br, txb, ptr, csr_s, csr_w, M);
  x1_kernel<<<(M * 100 + 255) / 256, 256, 0, stream>>>(Ar, txb, M * 100);

  // --- lins + z
  gemm_lin<<<dim3((100 + BN - 1) / BN, (M + BM - 1) / BM, 2), dim3(16, 16), 0, stream>>>(
      x, l1W, l1b, l2W, l2b, Ar /*x1*/, txb /*x2*/, Br /*z*/, M);

  // --- loss (pos+neg fused)
  loss_fused<<<1024, 256, 0, stream>>>(Br, ep, en, P, accs);

  // --- conv3 (propagate after GEMM: 2 dims)
  w3_kernel<<<(M + 255) / 256, 256, 0, stream>>>(txb /*x2*/, W3, b3, t0, t1, M);
  gather2<<<(M + 255) / 256, 256, 0, stream>>>(t1, tx3, ptr, csr_s, csr_w, M);

  final_kernel<<<(2 * M + 255) / 256, 256, 0, stream>>>(t0, tx3, accs, c1, c2, out, M, 1.0f / (float)P);
}

// Round 3
// 710.560 us; speedup vs baseline: 2.0133x; 1.3455x over previous
//
#include <hip/hip_runtime.h>
#include <math.h>

// MTGCN R2: bf16 MFMA GEMMs (16x16x32), bf16 gathers, bf16 loss reads.
// Propagate on the narrow side: conv1 before GEMM (128), conv2/conv3 after (100/2).
// CSR-gather (no atomics in propagation). absmax margin is ~175x, bf16 path is safe.

typedef unsigned short ushort_t;
typedef __attribute__((ext_vector_type(8))) __bf16 bf16x8;
typedef __attribute__((ext_vector_type(8))) short s16x8;
typedef __attribute__((ext_vector_type(4))) float f32x4;

__device__ __forceinline__ f32x4 mfma16x16x32(s16x8 a, s16x8 b, f32x4 c) {
  return __builtin_amdgcn_mfma_f32_16x16x32_bf16(
      __builtin_bit_cast(bf16x8, a), __builtin_bit_cast(bf16x8, b), c, 0, 0, 0);
}
__device__ __forceinline__ ushort_t f2bf(float f) {
  union { float f; unsigned u; } c; c.f = f;
  unsigned r = (c.u + 0x7FFFu + ((c.u >> 16) & 1u)) >> 16;
  return (ushort_t)r;
}
__device__ __forceinline__ float b2f(ushort_t h) {
  union { unsigned u; float f; } c; c.u = ((unsigned)h) << 16;
  return c.f;
}

// =======================================================================
// MFMA GEMM: block tile 64(M) x NT(N), 4 waves (2x2), wave tile 32 x NT/2.
// A sources bf16 row-major; Wt = B pre-transposed [NT][KTOT] bf16 (zero-padded).
// Frag layouts (m89/m91-verified): A: lane holds A[m=l&15][k=(l>>4)*8+j];
// B-operand == rows of Wt; C/D: col=l&15, row=(l>>4)*4+reg.
// VAR 0: conv1 (A=[xb|tx0b] K=256, out h bf16 [M][320], relu+b1, pad cols zero)
// VAR 1: conv2 (A=h [M][320], out0 Ar fp32 +b2 (col<100), out1 Brh bf16 (100..200))
// VAR 2: lins  (A=xb [M][128], out0 x2 fp32 = x1+relu(+l1b), out1 zh bf16 = x1+relu(+l2b))
// =======================================================================
template<int VAR, int NT, int KTOT>
__global__ __launch_bounds__(256) void gemm_mfma(
    const ushort_t* __restrict__ A0, const ushort_t* __restrict__ A1,
    const ushort_t* __restrict__ Wt,
    const float* __restrict__ bias0, const float* __restrict__ bias1,
    const float* __restrict__ x1,
    void* __restrict__ out0, void* __restrict__ out1, int M)
{
  constexpr int NF = NT / 32;            // B-frags per wave
  __shared__ __align__(16) ushort_t As[64 * 40];
  __shared__ __align__(16) ushort_t Bs[NT * 40];
  const int tid  = threadIdx.x;
  const int lane = tid & 63, w = tid >> 6;
  const int m0 = blockIdx.x * 64;
  const int wm = (w & 1) * 32, wn = (w >> 1) * (NT / 2);
  f32x4 acc[2][NF];
#pragma unroll
  for (int i = 0; i < 2; ++i)
#pragma unroll
    for (int j = 0; j < NF; ++j) acc[i][j] = (f32x4){0.f, 0.f, 0.f, 0.f};

  for (int k0 = 0; k0 < KTOT; k0 += 32) {
    { // A stage: 64 rows x 32 k (bf16), 4 threads/row x 16B
      const int r = tid >> 2, c8 = (tid & 3) * 8;
      const int gm = m0 + r;
      uint4 v = {0u, 0u, 0u, 0u};
      if (gm < M) {
        const ushort_t* src;
        if (VAR == 0) src = (k0 < 128) ? A0 + (size_t)gm * 128 + k0 + c8
                                       : A1 + (size_t)gm * 128 + (k0 - 128) + c8;
        else if (VAR == 1) src = A0 + (size_t)gm * 320 + k0 + c8;
        else src = A0 + (size_t)gm * 128 + k0 + c8;
        v = *(const uint4*)src;
      }
      *(uint4*)&As[r * 40 + c8] = v;
    }
    { // B stage: NT rows x 32 k
      const int c8 = (tid & 3) * 8;
#pragma unroll
      for (int i = 0; i < (NT * 4 + 255) / 256; ++i) {
        const int r = (tid >> 2) + i * 64;
        if (r < NT)
          *(uint4*)&Bs[r * 40 + c8] = *(const uint4*)(Wt + (size_t)r * KTOT + k0 + c8);
      }
    }
    __syncthreads();
    s16x8 af[2], bfr[NF];
#pragma unroll
    for (int mi = 0; mi < 2; ++mi)
      af[mi] = *(const s16x8*)&As[(wm + mi * 16 + (lane & 15)) * 40 + (lane >> 4) * 8];
#pragma unroll
    for (int ni = 0; ni < NF; ++ni)
      bfr[ni] = *(const s16x8*)&Bs[(wn + ni * 16 + (lane & 15)) * 40 + (lane >> 4) * 8];
#pragma unroll
    for (int mi = 0; mi < 2; ++mi)
#pragma unroll
      for (int ni = 0; ni < NF; ++ni)
        acc[mi][ni] = mfma16x16x32(af[mi], bfr[ni], acc[mi][ni]);
    __syncthreads();
  }

  // epilogue
#pragma unroll
  for (int mi = 0; mi < 2; ++mi)
#pragma unroll
    for (int ni = 0; ni < NF; ++ni)
#pragma unroll
      for (int r = 0; r < 4; ++r) {
        const int gRow = m0 + wm + mi * 16 + ((lane >> 4) << 2) + r;
        const int col  = wn + ni * 16 + (lane & 15);
        if (gRow >= M) continue;
        const float v = acc[mi][ni][r];
        if (VAR == 0) {
          ushort_t* h = (ushort_t*)out0;
          h[(size_t)gRow * 320 + col] = (col < 300) ? f2bf(fmaxf(v + bias0[col], 0.f))
                                                    : (ushort_t)0;
        } else if (VAR == 1) {
          if (col < 100) ((float*)out0)[(size_t)gRow * 100 + col] = v + bias0[col];
          else if (col < 200) ((ushort_t*)out1)[(size_t)gRow * 100 + (col - 100)] = f2bf(v);
        } else {
          if (col < 100) {
            const size_t idx = (size_t)gRow * 100 + col;
            ((float*)out0)[idx] = x1[idx] + fmaxf(v + bias0[col], 0.f);
          } else if (col < 200) {
            const int c = col - 100;
            const size_t idx = (size_t)gRow * 100 + c;
            ((ushort_t*)out1)[idx] = f2bf(x1[idx] + fmaxf(v + bias1[c], 0.f));
          }
        }
      }
}

// ---------------- packing / conversion ----------------
__global__ void cvt_x_kernel(const float* __restrict__ x, ushort_t* __restrict__ xb, int n) {
  const int i = blockIdx.x * 256 + threadIdx.x;
  if (i < n) xb[i] = f2bf(x[i]);
}
__global__ void pack_w1(const float* __restrict__ W1, ushort_t* __restrict__ W1t) {
  const int i = blockIdx.x * 256 + threadIdx.x;   // 320*256
  if (i >= 320 * 256) return;
  const int n = i >> 8, k = i & 255;
  float v = 0.f;
  if (n < 300) v = (k < 128) ? W1[k * 300 + n] : W1[38400 + (k - 128) * 300 + n];
  W1t[i] = f2bf(v);
}
__global__ void pack_w2(const float* __restrict__ W2, ushort_t* __restrict__ W2t) {
  const int i = blockIdx.x * 256 + threadIdx.x;   // 224*320
  if (i >= 224 * 320) return;
  const int n = i / 320, k = i - n * 320;
  float v = 0.f;
  if (n < 200 && k < 300) v = W2[(n < 100 ? 0 : 30000) + k * 100 + (n % 100)];
  W2t[i] = f2bf(v);
}
__global__ void pack_wl(const float* __restrict__ l1W, const float* __restrict__ l2W,
                        ushort_t* __restrict__ Wlt) {
  const int i = blockIdx.x * 256 + threadIdx.x;   // 224*128
  if (i >= 224 * 128) return;
  const int n = i >> 7, k = i & 127;
  float v = 0.f;
  if (n < 100) v = l1W[n * 128 + k];
  else if (n < 200) v = l2W[(n - 100) * 128 + k];
  Wlt[i] = f2bf(v);
}

// ---------------- degree + in-count, dinv
__global__ void deg_count_kernel(const int* __restrict__ src, const int* __restrict__ dst,
                                 float* __restrict__ deg, int* __restrict__ cnt, int E)
{
  const int e = blockIdx.x * blockDim.x + threadIdx.x;
  if (e < E) { atomicAdd(deg + src[e], 1.0f); atomicAdd(cnt + dst[e], 1); }
}
__global__ void dinv_kernel(float* __restrict__ d, int n) {
  const int i = blockIdx.x * blockDim.x + threadIdx.x;
  if (i < n) { const float v = d[i]; d[i] = (v > 0.f) ? 1.f / sqrtf(v) : 0.f; }
}

// ---------------- CSR build
__global__ void scan_local(const int* __restrict__ cnt, int* __restrict__ ptr,
                           int* __restrict__ bsum, int n)
{
  __shared__ int tmp[256];
  const int i = blockIdx.x * 256 + threadIdx.x;
  const int v = (i < n) ? cnt[i] : 0;
  tmp[threadIdx.x] = v;
  __syncthreads();
  for (int off = 1; off < 256; off <<= 1) {
    const int t = (threadIdx.x >= off) ? tmp[threadIdx.x - off] : 0;
    __syncthreads();
    tmp[threadIdx.x] += t;
    __syncthreads();
  }
  if (i < n) ptr[i] = tmp[threadIdx.x] - v;
  if (threadIdx.x == 255) bsum[blockIdx.x] = tmp[255];
}
__global__ void scan_bsum(int* __restrict__ bsum, int nb) {
  __shared__ int tmp[256];
  const int v = (threadIdx.x < nb) ? bsum[threadIdx.x] : 0;
  tmp[threadIdx.x] = v;
  __syncthreads();
  for (int off = 1; off < 256; off <<= 1) {
    const int t = (threadIdx.x >= off) ? tmp[threadIdx.x - off] : 0;
    __syncthreads();
    tmp[threadIdx.x] += t;
    __syncthreads();
  }
  if (threadIdx.x < nb) bsum[threadIdx.x] = tmp[threadIdx.x] - v;
}
__global__ void scan_add(int* __restrict__ ptr, const int* __restrict__ bsum, int n, int E) {
  const int i = blockIdx.x * 256 + threadIdx.x;
  if (i < n) ptr[i] += bsum[blockIdx.x];
  if (i == 0) ptr[n] = E;
}
__global__ void fill_csr(const int* __restrict__ src, const int* __restrict__ dst,
                         const float* __restrict__ dinv, int* __restrict__ cur,
                         int* __restrict__ cs, float* __restrict__ cw, int E)
{
  const int e = blockIdx.x * blockDim.x + threadIdx.x;
  if (e >= E) return;
  const int s = src[e], d = dst[e];
  const int pos = atomicAdd(cur + d, 1);
  cs[pos] = s;
  cw[pos] = -dinv[s] * dinv[d];
}

// ---------------- gathers (bf16 in, wave per dst node)
__global__ __launch_bounds__(256) void gather128h(
    const ushort_t* __restrict__ xb, ushort_t* __restrict__ txb,
    const int* __restrict__ ptr, const int* __restrict__ cs,
    const float* __restrict__ cw, int M)
{
  const int node = (blockIdx.x * 256 + threadIdx.x) >> 6;
  const int lane = threadIdx.x & 63;
  if (node >= M) return;
  const int beg = ptr[node], end = ptr[node + 1];
  float a0 = 0.f, a1 = 0.f;
  for (int p = beg; p < end; ++p) {
    const int s = cs[p]; const float w = cw[p];
    const unsigned v = *(const unsigned*)(xb + (size_t)s * 128 + lane * 2);
    a0 = fmaf(w, b2f((ushort_t)v), a0);
    a1 = fmaf(w, b2f((ushort_t)(v >> 16)), a1);
  }
  const unsigned o = (unsigned)f2bf(a0) | ((unsigned)f2bf(a1) << 16);
  *(unsigned*)(txb + (size_t)node * 128 + lane * 2) = o;
}
__global__ __launch_bounds__(256) void gather100h(
    const ushort_t* __restrict__ Brh, float* __restrict__ txg,
    const int* __restrict__ ptr, const int* __restrict__ cs,
    const float* __restrict__ cw, int M)
{
  const int node = (blockIdx.x * 256 + threadIdx.x) >> 6;
  const int lane = threadIdx.x & 63;
  if (node >= M) return;
  const int beg = ptr[node], end = ptr[node + 1];
  float a0 = 0.f, a1 = 0.f;
  for (int p = beg; p < end; ++p) {
    const int s = cs[p]; const float w = cw[p];
    if (lane < 50) {
      const unsigned v = *(const unsigned*)(Brh + (size_t)s * 100 + lane * 2);
      a0 = fmaf(w, b2f((ushort_t)v), a0);
      a1 = fmaf(w, b2f((ushort_t)(v >> 16)), a1);
    }
  }
  if (lane < 50)
    *(float2*)(txg + (size_t)node * 100 + lane * 2) = make_float2(a0, a1);
}
__global__ void gather2(
    const float* __restrict__ xin, float* __restrict__ xout,
    const int* __restrict__ ptr, const int* __restrict__ cs,
    const float* __restrict__ cw, int M)
{
  const int i = blockIdx.x * blockDim.x + threadIdx.x;
  if (i >= M) return;
  float a0 = 0.f, a1 = 0.f;
  const int beg = ptr[i], end = ptr[i + 1];
  for (int p = beg; p < end; ++p) {
    const int s = cs[p]; const float w = cw[p];
    const float2 v = *(const float2*)(xin + (size_t)s * 2);
    a0 = fmaf(w, v.x, a0); a1 = fmaf(w, v.y, a1);
  }
  *(float2*)(xout + (size_t)i * 2) = make_float2(a0, a1);
}

// ---------------- x1 = relu(Ar + tx) in place
__global__ void x1_kernel(float* __restrict__ a, const float* __restrict__ tx, int n) {
  const int i = blockIdx.x * blockDim.x + threadIdx.x;
  if (i < n) a[i] = fmaxf(a[i] + tx[i], 0.f);
}

// ---------------- conv3: t0 = x2@W3[0]+b3, t1 = x2@W3[1]
__global__ __launch_bounds__(256) void w3_kernel(
    const float* __restrict__ x2, const float* __restrict__ W3,
    const float* __restrict__ b3, float* __restrict__ t0, float* __restrict__ t1, int M)
{
  __shared__ float w[400];
  for (int i = threadIdx.x; i < 400; i += 256) w[i] = W3[i];
  __syncthreads();
  const int m = blockIdx.x * 256 + threadIdx.x;
  if (m >= M) return;
  const float4* row = (const float4*)(x2 + (size_t)m * 100);
  float a0 = 0.f, a1 = 0.f, c0 = 0.f, c1v = 0.f;
#pragma unroll
  for (int q = 0; q < 25; ++q) {
    const float4 v = row[q];
    const int k2 = q * 8;
    a0 = fmaf(v.x, w[k2 + 0], a0); a1 = fmaf(v.x, w[k2 + 1], a1);
    a0 = fmaf(v.y, w[k2 + 2], a0); a1 = fmaf(v.y, w[k2 + 3], a1);
    a0 = fmaf(v.z, w[k2 + 4], a0); a1 = fmaf(v.z, w[k2 + 5], a1);
    a0 = fmaf(v.w, w[k2 + 6], a0); a1 = fmaf(v.w, w[k2 + 7], a1);
    c0 = fmaf(v.x, w[200 + k2 + 0], c0); c1v = fmaf(v.x, w[200 + k2 + 1], c1v);
    c0 = fmaf(v.y, w[200 + k2 + 2], c0); c1v = fmaf(v.y, w[200 + k2 + 3], c1v);
    c0 = fmaf(v.z, w[200 + k2 + 4], c0); c1v = fmaf(v.z, w[200 + k2 + 5], c1v);
    c0 = fmaf(v.w, w[200 + k2 + 6], c0); c1v = fmaf(v.w, w[200 + k2 + 7], c1v);
  }
  t0[(size_t)m * 2 + 0] = a0 + b3[0];
  t0[(size_t)m * 2 + 1] = a1 + b3[1];
  t1[(size_t)m * 2 + 0] = c0;
  t1[(size_t)m * 2 + 1] = c1v;
}

// ---------------- loss: 2 pairs per wave (32-lane halves), bf16 z rows
__global__ __launch_bounds__(256) void loss_bf16(
    const ushort_t* __restrict__ zh, const int* __restrict__ ep,
    const int* __restrict__ en, int P, float* __restrict__ acc)
{
  __shared__ float red[8];
  const int tid = threadIdx.x;
  const int lane = tid & 63, wib = tid >> 6;
  const int half = lane >> 5, sub = lane & 31;
  const int slot0 = blockIdx.x * 8 + wib * 2 + half;
  const int nslots = gridDim.x * 8;
  float tp = 0.f, tn = 0.f;
  for (int g = slot0; g < 2 * P; g += nslots) {
    const int neg = (g >= P);
    const int p = neg ? g - P : g;
    const int* ia = neg ? en : ep;
    const int na = ia[p], nb = ia[P + p];
    float s = 0.f;
    if (sub < 25) {
      const ushort4 a = *(const ushort4*)(zh + (size_t)na * 100 + sub * 4);
      const ushort4 b = *(const ushort4*)(zh + (size_t)nb * 100 + sub * 4);
      s = b2f(a.x) * b2f(b.x) + b2f(a.y) * b2f(b.y)
        + b2f(a.z) * b2f(b.z) + b2f(a.w) * b2f(b.w);
    }
#pragma unroll
    for (int off = 16; off; off >>= 1) s += __shfl_down(s, off, 32);
    if (sub == 0) {
      const float sig = 1.f / (1.f + expf(-s));   // JAX f32 semantics
      if (neg) tn += logf(1.f - sig + 1e-15f);
      else     tp += logf(sig + 1e-15f);
    }
  }
  tp += __shfl_down(tp, 32, 64);
  tn += __shfl_down(tn, 32, 64);
  if (lane == 0) { red[wib] = tp; red[4 + wib] = tn; }
  __syncthreads();
  if (tid == 0) {
    atomicAdd(acc + 0, red[0] + red[1] + red[2] + red[3]);
    atomicAdd(acc + 1, red[4] + red[5] + red[6] + red[7]);
  }
}

// ---------------- final
__global__ void final_kernel(const float* __restrict__ t0, const float* __restrict__ tx3,
                             const float* __restrict__ accs, const float* __restrict__ c1,
                             const float* __restrict__ c2, float* __restrict__ out,
                             int M, float invP)
{
  const int i = blockIdx.x * blockDim.x + threadIdx.x;
  if (i < 2 * M) out[i] = t0[i] + tx3[i];
  if (i == 0) {
    out[2 * M + 0] = -(accs[0] + accs[1]) * invP;
    out[2 * M + 1] = c1[0];
    out[2 * M + 2] = c2[0];
  }
}

extern "C" void kernel_launch(void* const* d_in, const int* in_sizes, int n_in,
                              void* d_out, int out_size, void* d_ws, size_t ws_size,
                              hipStream_t stream)
{
  const float* x   = (const float*)d_in[0];
  const int*   ei  = (const int*)d_in[1];
  const int*   ep  = (const int*)d_in[2];
  const int*   en  = (const int*)d_in[3];
  const float* W1  = (const float*)d_in[4];
  const float* b1  = (const float*)d_in[5];
  const float* W2  = (const float*)d_in[6];
  const float* b2  = (const float*)d_in[7];
  const float* W3  = (const float*)d_in[8];
  const float* b3  = (const float*)d_in[9];
  const float* l1W = (const float*)d_in[10];
  const float* l1b = (const float*)d_in[11];
  const float* l2W = (const float*)d_in[12];
  const float* l2b = (const float*)d_in[13];
  const float* c1  = (const float*)d_in[14];
  const float* c2  = (const float*)d_in[15];
  float* out = (float*)d_out;

  const int M = in_sizes[0] / 128;  // 50000
  const int E = in_sizes[1] / 2;    // 800000
  const int P = in_sizes[2] / 2;    // 400000
  const int* src = ei;
  const int* dst = ei + E;
  const int nb_scan = (M + 255) / 256;

  // workspace layout (4-byte words, all chunk sizes multiple of 4 words)
  float* ws = (float*)d_ws;
  size_t o = 0;
  float*    dinv = ws + o;            o += 50176;
  int*      cnt  = (int*)(ws + o);    o += (size_t)M;
  int*      ptr  = (int*)(ws + o);    o += (size_t)M + 8;
  int*      cur  = (int*)(ws + o);    o += (size_t)M;
  int*      bsum = (int*)(ws + o);    o += 256;
  int*      csr_s = (int*)(ws + o);   o += (size_t)E;
  float*    csr_w = ws + o;           o += (size_t)E;
  ushort_t* xb   = (ushort_t*)(ws + o); o += (size_t)M * 64;   // x bf16 [M][128]
  ushort_t* tx0b = (ushort_t*)(ws + o); o += (size_t)M * 64;   // L_hat x bf16 [M][128]
  ushort_t* W1t  = (ushort_t*)(ws + o); o += 40960;            // [320][256]
  ushort_t* W2t  = (ushort_t*)(ws + o); o += 35840;            // [224][320]
  ushort_t* Wlt  = (ushort_t*)(ws + o); o += 14336;            // [224][128]
  ushort_t* h    = (ushort_t*)(ws + o); o += (size_t)M * 160;  // conv1 out bf16 [M][320]
  float*    Ar   = ws + o;            o += (size_t)M * 100;    // conv2[0]+b2 -> x1
  ushort_t* Brh  = (ushort_t*)(ws + o); o += (size_t)M * 50;   // conv2[1] bf16 [M][100]
  float*    txg  = ws + o;            o += (size_t)M * 100;    // gather100 out fp32
  float*    x2   = ws + o;            o += (size_t)M * 100;
  ushort_t* zh   = (ushort_t*)(ws + o); o += (size_t)M * 50;   // z bf16 [M][100]
  float*    t0   = ws + o;            o += (size_t)M * 2;
  float*    t1   = ws + o;            o += (size_t)M * 2;
  float*    tx3  = ws + o;            o += (size_t)M * 2;
  float*    accs = ws + o;            o += 8;

  hipMemsetAsync(dinv, 0, (size_t)M * 4, stream);
  hipMemsetAsync(cnt,  0, (size_t)M * 4, stream);
  hipMemsetAsync(accs, 0, 2 * 4, stream);

  // --- packing (independent, early)
  cvt_x_kernel<<<(M * 128 + 255) / 256, 256, 0, stream>>>(x, xb, M * 128);
  pack_w1<<<(320 * 256 + 255) / 256, 256, 0, stream>>>(W1, W1t);
  pack_w2<<<(224 * 320 + 255) / 256, 256, 0, stream>>>(W2, W2t);
  pack_wl<<<(224 * 128 + 255) / 256, 256, 0, stream>>>(l1W, l2W, Wlt);

  // --- CSR build
  deg_count_kernel<<<(E + 255) / 256, 256, 0, stream>>>(src, dst, dinv, cnt, E);
  dinv_kernel<<<(M + 255) / 256, 256, 0, stream>>>(dinv, M);
  scan_local<<<nb_scan, 256, 0, stream>>>(cnt, ptr, bsum, M);
  scan_bsum<<<1, 256, 0, stream>>>(bsum, nb_scan);
  scan_add<<<nb_scan, 256, 0, stream>>>(ptr, bsum, M, E);
  hipMemcpyAsync(cur, ptr, (size_t)M * 4, hipMemcpyDeviceToDevice, stream);
  fill_csr<<<(E + 255) / 256, 256, 0, stream>>>(src, dst, dinv, cur, csr_s, csr_w, E);

  const int gB = (M + 63) / 64;

  // --- conv1: h = relu([xb|tx0b] @ W1t^T + b1), bf16 MFMA
  gather128h<<<(M * 64 + 255) / 256, 256, 0, stream>>>(xb, tx0b, ptr, csr_s, csr_w, M);
  gemm_mfma<0, 320, 256><<<gB, 256, 0, stream>>>(xb, tx0b, W1t, b1, nullptr, nullptr, h, nullptr, M);

  // --- conv2: Ar = h@W2[0]+b2 (fp32), Brh = h@W2[1] (bf16)
  gemm_mfma<1, 224, 320><<<gB, 256, 0, stream>>>(h, nullptr, W2t, b2, nullptr, nullptr, Ar, Brh, M);
  gather100h<<<(M * 64 + 255) / 256, 256, 0, stream>>>(Brh, txg, ptr, csr_s, csr_w, M);
  x1_kernel<<<(M * 100 + 255) / 256, 256, 0, stream>>>(Ar, txg, M * 100);

  // --- lins: x2 = x1+relu(x@l1W^T+b) fp32 ; zh = bf16(x1+relu(x@l2W^T+b))
  gemm_mfma<2, 224, 128><<<gB, 256, 0, stream>>>(xb, nullptr, Wlt, l1b, l2b, Ar /*x1*/, x2, zh, M);

  // --- loss
  loss_bf16<<<1024, 256, 0, stream>>>(zh, ep, en, P, accs);

  // --- conv3
  w3_kernel<<<(M + 255) / 256, 256, 0, stream>>>(x2, W3, b3, t0, t1, M);
  gather2<<<(M + 255) / 256, 256, 0, stream>>>(t1, tx3, ptr, csr_s, csr_w, M);

  final_kernel<<<(2 * M + 255) / 256, 256, 0, stream>>>(t0, tx3, accs, c1, c2, out, M, 1.0f / (float)P);
}

// Round 4
// 580.299 us; speedup vs baseline: 2.4653x; 1.2245x over previous
//
#include <hip/hip_runtime.h>
#include <math.h>

// MTGCN R3: bf16 MFMA GEMMs; latency-optimized gathers (4-way ILP unroll) and
// loss (2x grid + 2-way ILP); fused gather100+x1 and gather2+final.
// Propagate on the narrow side: conv1 before GEMM (128), conv2/conv3 after (100/2).

typedef unsigned short ushort_t;
typedef __attribute__((ext_vector_type(8))) __bf16 bf16x8;
typedef __attribute__((ext_vector_type(8))) short s16x8;
typedef __attribute__((ext_vector_type(4))) float f32x4;

__device__ __forceinline__ f32x4 mfma16x16x32(s16x8 a, s16x8 b, f32x4 c) {
  return __builtin_amdgcn_mfma_f32_16x16x32_bf16(
      __builtin_bit_cast(bf16x8, a), __builtin_bit_cast(bf16x8, b), c, 0, 0, 0);
}
__device__ __forceinline__ ushort_t f2bf(float f) {
  union { float f; unsigned u; } c; c.f = f;
  unsigned r = (c.u + 0x7FFFu + ((c.u >> 16) & 1u)) >> 16;
  return (ushort_t)r;
}
__device__ __forceinline__ float b2f(ushort_t h) {
  union { unsigned u; float f; } c; c.u = ((unsigned)h) << 16;
  return c.f;
}

// =======================================================================
// MFMA GEMM: block tile 64(M) x NT(N), 4 waves (2x2), wave tile 32 x NT/2.
// VAR 0: conv1 (A=[xb|tx0b] K=256, out h bf16 [M][320], relu+b1)
// VAR 1: conv2 (A=h [M][320], out0 Ar fp32 +b2 (col<100), out1 Brh bf16 (100..200))
// VAR 2: lins  (A=xb [M][128], out0 x2 fp32 = x1+relu(+l1b), out1 zh bf16 = x1+relu(+l2b))
// =======================================================================
template<int VAR, int NT, int KTOT>
__global__ __launch_bounds__(256) void gemm_mfma(
    const ushort_t* __restrict__ A0, const ushort_t* __restrict__ A1,
    const ushort_t* __restrict__ Wt,
    const float* __restrict__ bias0, const float* __restrict__ bias1,
    const float* __restrict__ x1,
    void* __restrict__ out0, void* __restrict__ out1, int M)
{
  constexpr int NF = NT / 32;
  __shared__ __align__(16) ushort_t As[64 * 40];
  __shared__ __align__(16) ushort_t Bs[NT * 40];
  const int tid  = threadIdx.x;
  const int lane = tid & 63, w = tid >> 6;
  const int m0 = blockIdx.x * 64;
  const int wm = (w & 1) * 32, wn = (w >> 1) * (NT / 2);
  f32x4 acc[2][NF];
#pragma unroll
  for (int i = 0; i < 2; ++i)
#pragma unroll
    for (int j = 0; j < NF; ++j) acc[i][j] = (f32x4){0.f, 0.f, 0.f, 0.f};

  for (int k0 = 0; k0 < KTOT; k0 += 32) {
    { // A stage
      const int r = tid >> 2, c8 = (tid & 3) * 8;
      const int gm = m0 + r;
      uint4 v = {0u, 0u, 0u, 0u};
      if (gm < M) {
        const ushort_t* src;
        if (VAR == 0) src = (k0 < 128) ? A0 + (size_t)gm * 128 + k0 + c8
                                       : A1 + (size_t)gm * 128 + (k0 - 128) + c8;
        else if (VAR == 1) src = A0 + (size_t)gm * 320 + k0 + c8;
        else src = A0 + (size_t)gm * 128 + k0 + c8;
        v = *(const uint4*)src;
      }
      *(uint4*)&As[r * 40 + c8] = v;
    }
    { // B stage
      const int c8 = (tid & 3) * 8;
#pragma unroll
      for (int i = 0; i < (NT * 4 + 255) / 256; ++i) {
        const int r = (tid >> 2) + i * 64;
        if (r < NT)
          *(uint4*)&Bs[r * 40 + c8] = *(const uint4*)(Wt + (size_t)r * KTOT + k0 + c8);
      }
    }
    __syncthreads();
    s16x8 af[2], bfr[NF];
#pragma unroll
    for (int mi = 0; mi < 2; ++mi)
      af[mi] = *(const s16x8*)&As[(wm + mi * 16 + (lane & 15)) * 40 + (lane >> 4) * 8];
#pragma unroll
    for (int ni = 0; ni < NF; ++ni)
      bfr[ni] = *(const s16x8*)&Bs[(wn + ni * 16 + (lane & 15)) * 40 + (lane >> 4) * 8];
#pragma unroll
    for (int mi = 0; mi < 2; ++mi)
#pragma unroll
      for (int ni = 0; ni < NF; ++ni)
        acc[mi][ni] = mfma16x16x32(af[mi], bfr[ni], acc[mi][ni]);
    __syncthreads();
  }

#pragma unroll
  for (int mi = 0; mi < 2; ++mi)
#pragma unroll
    for (int ni = 0; ni < NF; ++ni)
#pragma unroll
      for (int r = 0; r < 4; ++r) {
        const int gRow = m0 + wm + mi * 16 + ((lane >> 4) << 2) + r;
        const int col  = wn + ni * 16 + (lane & 15);
        if (gRow >= M) continue;
        const float v = acc[mi][ni][r];
        if (VAR == 0) {
          ushort_t* h = (ushort_t*)out0;
          h[(size_t)gRow * 320 + col] = (col < 300) ? f2bf(fmaxf(v + bias0[col], 0.f))
                                                    : (ushort_t)0;
        } else if (VAR == 1) {
          if (col < 100) ((float*)out0)[(size_t)gRow * 100 + col] = v + bias0[col];
          else if (col < 200) ((ushort_t*)out1)[(size_t)gRow * 100 + (col - 100)] = f2bf(v);
        } else {
          if (col < 100) {
            const size_t idx = (size_t)gRow * 100 + col;
            ((float*)out0)[idx] = x1[idx] + fmaxf(v + bias0[col], 0.f);
          } else if (col < 200) {
            const int c = col - 100;
            const size_t idx = (size_t)gRow * 100 + c;
            ((ushort_t*)out1)[idx] = f2bf(x1[idx] + fmaxf(v + bias1[c], 0.f));
          }
        }
      }
}

// ---------------- packing / conversion ----------------
__global__ void cvt_x_kernel(const float* __restrict__ x, ushort_t* __restrict__ xb, int n) {
  const int i = blockIdx.x * 256 + threadIdx.x;
  if (i < n) xb[i] = f2bf(x[i]);
}
__global__ void pack_w1(const float* __restrict__ W1, ushort_t* __restrict__ W1t) {
  const int i = blockIdx.x * 256 + threadIdx.x;
  if (i >= 320 * 256) return;
  const int n = i >> 8, k = i & 255;
  float v = 0.f;
  if (n < 300) v = (k < 128) ? W1[k * 300 + n] : W1[38400 + (k - 128) * 300 + n];
  W1t[i] = f2bf(v);
}
__global__ void pack_w2(const float* __restrict__ W2, ushort_t* __restrict__ W2t) {
  const int i = blockIdx.x * 256 + threadIdx.x;
  if (i >= 224 * 320) return;
  const int n = i / 320, k = i - n * 320;
  float v = 0.f;
  if (n < 200 && k < 300) v = W2[(n < 100 ? 0 : 30000) + k * 100 + (n % 100)];
  W2t[i] = f2bf(v);
}
__global__ void pack_wl(const float* __restrict__ l1W, const float* __restrict__ l2W,
                        ushort_t* __restrict__ Wlt) {
  const int i = blockIdx.x * 256 + threadIdx.x;
  if (i >= 224 * 128) return;
  const int n = i >> 7, k = i & 127;
  float v = 0.f;
  if (n < 100) v = l1W[n * 128 + k];
  else if (n < 200) v = l2W[(n - 100) * 128 + k];
  Wlt[i] = f2bf(v);
}

// ---------------- degree + in-count, dinv
__global__ void deg_count_kernel(const int* __restrict__ src, const int* __restrict__ dst,
                                 float* __restrict__ deg, int* __restrict__ cnt, int E)
{
  const int e = blockIdx.x * blockDim.x + threadIdx.x;
  if (e < E) { atomicAdd(deg + src[e], 1.0f); atomicAdd(cnt + dst[e], 1); }
}
__global__ void dinv_kernel(float* __restrict__ d, int n) {
  const int i = blockIdx.x * blockDim.x + threadIdx.x;
  if (i < n) { const float v = d[i]; d[i] = (v > 0.f) ? 1.f / sqrtf(v) : 0.f; }
}

// ---------------- CSR build
__global__ void scan_local(const int* __restrict__ cnt, int* __restrict__ ptr,
                           int* __restrict__ bsum, int n)
{
  __shared__ int tmp[256];
  const int i = blockIdx.x * 256 + threadIdx.x;
  const int v = (i < n) ? cnt[i] : 0;
  tmp[threadIdx.x] = v;
  __syncthreads();
  for (int off = 1; off < 256; off <<= 1) {
    const int t = (threadIdx.x >= off) ? tmp[threadIdx.x - off] : 0;
    __syncthreads();
    tmp[threadIdx.x] += t;
    __syncthreads();
  }
  if (i < n) ptr[i] = tmp[threadIdx.x] - v;
  if (threadIdx.x == 255) bsum[blockIdx.x] = tmp[255];
}
__global__ void scan_bsum(int* __restrict__ bsum, int nb) {
  __shared__ int tmp[256];
  const int v = (threadIdx.x < nb) ? bsum[threadIdx.x] : 0;
  tmp[threadIdx.x] = v;
  __syncthreads();
  for (int off = 1; off < 256; off <<= 1) {
    const int t = (threadIdx.x >= off) ? tmp[threadIdx.x - off] : 0;
    __syncthreads();
    tmp[threadIdx.x] += t;
    __syncthreads();
  }
  if (threadIdx.x < nb) bsum[threadIdx.x] = tmp[threadIdx.x] - v;
}
__global__ void scan_add(int* __restrict__ ptr, const int* __restrict__ bsum, int n, int E) {
  const int i = blockIdx.x * 256 + threadIdx.x;
  if (i < n) ptr[i] += bsum[blockIdx.x];
  if (i == 0) ptr[n] = E;
}
__global__ void fill_csr(const int* __restrict__ src, const int* __restrict__ dst,
                         const float* __restrict__ dinv, int* __restrict__ cur,
                         int* __restrict__ cs, float* __restrict__ cw, int E)
{
  const int e = blockIdx.x * blockDim.x + threadIdx.x;
  if (e >= E) return;
  const int s = src[e], d = dst[e];
  const int pos = atomicAdd(cur + d, 1);
  cs[pos] = s;
  cw[pos] = -dinv[s] * dinv[d];
}

// ---------------- gather128 (bf16), 4-way ILP unroll
__global__ __launch_bounds__(256) void gather128h(
    const ushort_t* __restrict__ xb, ushort_t* __restrict__ txb,
    const int* __restrict__ ptr, const int* __restrict__ cs,
    const float* __restrict__ cw, int M)
{
  const int node = (blockIdx.x * 256 + threadIdx.x) >> 6;
  const int lane = threadIdx.x & 63;
  if (node >= M) return;
  const int beg = ptr[node], end = ptr[node + 1];
  float a0 = 0.f, a1 = 0.f;
  int p = beg;
  for (; p + 4 <= end; p += 4) {
    const int s0 = cs[p], s1 = cs[p + 1], s2 = cs[p + 2], s3 = cs[p + 3];
    const float w0 = cw[p], w1 = cw[p + 1], w2 = cw[p + 2], w3 = cw[p + 3];
    const unsigned v0 = *(const unsigned*)(xb + (size_t)s0 * 128 + lane * 2);
    const unsigned v1 = *(const unsigned*)(xb + (size_t)s1 * 128 + lane * 2);
    const unsigned v2 = *(const unsigned*)(xb + (size_t)s2 * 128 + lane * 2);
    const unsigned v3 = *(const unsigned*)(xb + (size_t)s3 * 128 + lane * 2);
    a0 = fmaf(w0, b2f((ushort_t)v0), a0); a1 = fmaf(w0, b2f((ushort_t)(v0 >> 16)), a1);
    a0 = fmaf(w1, b2f((ushort_t)v1), a0); a1 = fmaf(w1, b2f((ushort_t)(v1 >> 16)), a1);
    a0 = fmaf(w2, b2f((ushort_t)v2), a0); a1 = fmaf(w2, b2f((ushort_t)(v2 >> 16)), a1);
    a0 = fmaf(w3, b2f((ushort_t)v3), a0); a1 = fmaf(w3, b2f((ushort_t)(v3 >> 16)), a1);
  }
  for (; p < end; ++p) {
    const int s = cs[p]; const float w = cw[p];
    const unsigned v = *(const unsigned*)(xb + (size_t)s * 128 + lane * 2);
    a0 = fmaf(w, b2f((ushort_t)v), a0);
    a1 = fmaf(w, b2f((ushort_t)(v >> 16)), a1);
  }
  const unsigned o = (unsigned)f2bf(a0) | ((unsigned)f2bf(a1) << 16);
  *(unsigned*)(txb + (size_t)node * 128 + lane * 2) = o;
}

// ---------------- fused gather100 + x1: x1 = relu(Ar + L_hat(Brh)), in place over Ar
__global__ __launch_bounds__(256) void gather100_x1(
    const ushort_t* __restrict__ Brh, float* __restrict__ Ar,
    const int* __restrict__ ptr, const int* __restrict__ cs,
    const float* __restrict__ cw, int M)
{
  const int node = (blockIdx.x * 256 + threadIdx.x) >> 6;
  const int lane = threadIdx.x & 63;
  if (node >= M) return;
  const int beg = ptr[node], end = ptr[node + 1];
  const bool act = lane < 50;
  float a0 = 0.f, a1 = 0.f;
  int p = beg;
  for (; p + 4 <= end; p += 4) {
    const int s0 = cs[p], s1 = cs[p + 1], s2 = cs[p + 2], s3 = cs[p + 3];
    const float w0 = cw[p], w1 = cw[p + 1], w2 = cw[p + 2], w3 = cw[p + 3];
    if (act) {
      const unsigned v0 = *(const unsigned*)(Brh + (size_t)s0 * 100 + lane * 2);
      const unsigned v1 = *(const unsigned*)(Brh + (size_t)s1 * 100 + lane * 2);
      const unsigned v2 = *(const unsigned*)(Brh + (size_t)s2 * 100 + lane * 2);
      const unsigned v3 = *(const unsigned*)(Brh + (size_t)s3 * 100 + lane * 2);
      a0 = fmaf(w0, b2f((ushort_t)v0), a0); a1 = fmaf(w0, b2f((ushort_t)(v0 >> 16)), a1);
      a0 = fmaf(w1, b2f((ushort_t)v1), a0); a1 = fmaf(w1, b2f((ushort_t)(v1 >> 16)), a1);
      a0 = fmaf(w2, b2f((ushort_t)v2), a0); a1 = fmaf(w2, b2f((ushort_t)(v2 >> 16)), a1);
      a0 = fmaf(w3, b2f((ushort_t)v3), a0); a1 = fmaf(w3, b2f((ushort_t)(v3 >> 16)), a1);
    }
  }
  for (; p < end; ++p) {
    const int s = cs[p]; const float w = cw[p];
    if (act) {
      const unsigned v = *(const unsigned*)(Brh + (size_t)s * 100 + lane * 2);
      a0 = fmaf(w, b2f((ushort_t)v), a0);
      a1 = fmaf(w, b2f((ushort_t)(v >> 16)), a1);
    }
  }
  if (act) {
    float* dst = Ar + (size_t)node * 100 + lane * 2;
    const float2 base = *(const float2*)dst;
    *(float2*)dst = make_float2(fmaxf(base.x + a0, 0.f), fmaxf(base.y + a1, 0.f));
  }
}

// ---------------- conv3: t0 = x2@W3[0]+b3, t1 = x2@W3[1]
__global__ __launch_bounds__(256) void w3_kernel(
    const float* __restrict__ x2, const float* __restrict__ W3,
    const float* __restrict__ b3, float* __restrict__ t0, float* __restrict__ t1, int M)
{
  __shared__ float w[400];
  for (int i = threadIdx.x; i < 400; i += 256) w[i] = W3[i];
  __syncthreads();
  const int m = blockIdx.x * 256 + threadIdx.x;
  if (m >= M) return;
  const float4* row = (const float4*)(x2 + (size_t)m * 100);
  float a0 = 0.f, a1 = 0.f, c0 = 0.f, c1v = 0.f;
#pragma unroll
  for (int q = 0; q < 25; ++q) {
    const float4 v = row[q];
    const int k2 = q * 8;
    a0 = fmaf(v.x, w[k2 + 0], a0); a1 = fmaf(v.x, w[k2 + 1], a1);
    a0 = fmaf(v.y, w[k2 + 2], a0); a1 = fmaf(v.y, w[k2 + 3], a1);
    a0 = fmaf(v.z, w[k2 + 4], a0); a1 = fmaf(v.z, w[k2 + 5], a1);
    a0 = fmaf(v.w, w[k2 + 6], a0); a1 = fmaf(v.w, w[k2 + 7], a1);
    c0 = fmaf(v.x, w[200 + k2 + 0], c0); c1v = fmaf(v.x, w[200 + k2 + 1], c1v);
    c0 = fmaf(v.y, w[200 + k2 + 2], c0); c1v = fmaf(v.y, w[200 + k2 + 3], c1v);
    c0 = fmaf(v.z, w[200 + k2 + 4], c0); c1v = fmaf(v.z, w[200 + k2 + 5], c1v);
    c0 = fmaf(v.w, w[200 + k2 + 6], c0); c1v = fmaf(v.w, w[200 + k2 + 7], c1v);
  }
  t0[(size_t)m * 2 + 0] = a0 + b3[0];
  t0[(size_t)m * 2 + 1] = a1 + b3[1];
  t1[(size_t)m * 2 + 0] = c0;
  t1[(size_t)m * 2 + 1] = c1v;
}

// ---------------- loss: 2 pairs per 32-lane half, 2-way ILP grid-stride
__global__ __launch_bounds__(256) void loss_bf16(
    const ushort_t* __restrict__ zh, const int* __restrict__ ep,
    const int* __restrict__ en, int P, float* __restrict__ acc)
{
  __shared__ float red[8];
  const int tid = threadIdx.x;
  const int lane = tid & 63, wib = tid >> 6;
  const int half = lane >> 5, sub = lane & 31;
  const int slot0 = blockIdx.x * 8 + wib * 2 + half;
  const int step = gridDim.x * 8;
  float tp = 0.f, tn = 0.f;
  int g = slot0;
  for (; g + step < 2 * P; g += 2 * step) {
    const int gA = g, gB = g + step;
    const int negA = (gA >= P), negB = (gB >= P);
    const int pA = negA ? gA - P : gA, pB = negB ? gB - P : gB;
    const int* iA = negA ? en : ep;
    const int* iB = negB ? en : ep;
    const int naA = iA[pA], nbA = iA[P + pA];
    const int naB = iB[pB], nbB = iB[P + pB];
    float sA = 0.f, sB = 0.f;
    if (sub < 25) {
      const ushort4 a1 = *(const ushort4*)(zh + (size_t)naA * 100 + sub * 4);
      const ushort4 b1 = *(const ushort4*)(zh + (size_t)nbA * 100 + sub * 4);
      const ushort4 a2 = *(const ushort4*)(zh + (size_t)naB * 100 + sub * 4);
      const ushort4 b2 = *(const ushort4*)(zh + (size_t)nbB * 100 + sub * 4);
      sA = b2f(a1.x) * b2f(b1.x) + b2f(a1.y) * b2f(b1.y)
         + b2f(a1.z) * b2f(b1.z) + b2f(a1.w) * b2f(b1.w);
      sB = b2f(a2.x) * b2f(b2.x) + b2f(a2.y) * b2f(b2.y)
         + b2f(a2.z) * b2f(b2.z) + b2f(a2.w) * b2f(b2.w);
    }
#pragma unroll
    for (int off = 16; off; off >>= 1) {
      sA += __shfl_down(sA, off, 32);
      sB += __shfl_down(sB, off, 32);
    }
    if (sub == 0) {
      const float sigA = 1.f / (1.f + expf(-sA));
      if (negA) tn += logf(1.f - sigA + 1e-15f); else tp += logf(sigA + 1e-15f);
      const float sigB = 1.f / (1.f + expf(-sB));
      if (negB) tn += logf(1.f - sigB + 1e-15f); else tp += logf(sigB + 1e-15f);
    }
  }
  if (g < 2 * P) {
    const int neg = (g >= P);
    const int p = neg ? g - P : g;
    const int* ia = neg ? en : ep;
    const int na = ia[p], nb = ia[P + p];
    float s = 0.f;
    if (sub < 25) {
      const ushort4 a = *(const ushort4*)(zh + (size_t)na * 100 + sub * 4);
      const ushort4 b = *(const ushort4*)(zh + (size_t)nb * 100 + sub * 4);
      s = b2f(a.x) * b2f(b.x) + b2f(a.y) * b2f(b.y)
        + b2f(a.z) * b2f(b.z) + b2f(a.w) * b2f(b.w);
    }
#pragma unroll
    for (int off = 16; off; off >>= 1) s += __shfl_down(s, off, 32);
    if (sub == 0) {
      const float sig = 1.f / (1.f + expf(-s));
      if (neg) tn += logf(1.f - sig + 1e-15f); else tp += logf(sig + 1e-15f);
    }
  }
  tp += __shfl_down(tp, 32, 64);
  tn += __shfl_down(tn, 32, 64);
  if (lane == 0) { red[wib] = tp; red[4 + wib] = tn; }
  __syncthreads();
  if (tid == 0) {
    atomicAdd(acc + 0, red[0] + red[1] + red[2] + red[3]);
    atomicAdd(acc + 1, red[4] + red[5] + red[6] + red[7]);
  }
}

// ---------------- fused gather2 + final: out = t0 + L_hat(t1), plus loss/scalars
__global__ void gather2_final(
    const float* __restrict__ t1, const float* __restrict__ t0,
    const int* __restrict__ ptr, const int* __restrict__ cs,
    const float* __restrict__ cw, const float* __restrict__ accs,
    const float* __restrict__ c1, const float* __restrict__ c2,
    float* __restrict__ out, int M, float invP)
{
  const int i = blockIdx.x * blockDim.x + threadIdx.x;
  if (i < M) {
    float a0 = 0.f, a1 = 0.f;
    const int beg = ptr[i], end = ptr[i + 1];
    int p = beg;
    for (; p + 4 <= end; p += 4) {
      const int s0 = cs[p], s1 = cs[p + 1], s2 = cs[p + 2], s3 = cs[p + 3];
      const float w0 = cw[p], w1 = cw[p + 1], w2 = cw[p + 2], w3 = cw[p + 3];
      const float2 v0 = *(const float2*)(t1 + (size_t)s0 * 2);
      const float2 v1 = *(const float2*)(t1 + (size_t)s1 * 2);
      const float2 v2 = *(const float2*)(t1 + (size_t)s2 * 2);
      const float2 v3 = *(const float2*)(t1 + (size_t)s3 * 2);
      a0 = fmaf(w0, v0.x, a0); a1 = fmaf(w0, v0.y, a1);
      a0 = fmaf(w1, v1.x, a0); a1 = fmaf(w1, v1.y, a1);
      a0 = fmaf(w2, v2.x, a0); a1 = fmaf(w2, v2.y, a1);
      a0 = fmaf(w3, v3.x, a0); a1 = fmaf(w3, v3.y, a1);
    }
    for (; p < end; ++p) {
      const int s = cs[p]; const float w = cw[p];
      const float2 v = *(const float2*)(t1 + (size_t)s * 2);
      a0 = fmaf(w, v.x, a0); a1 = fmaf(w, v.y, a1);
    }
    const float2 base = *(const float2*)(t0 + (size_t)i * 2);
    *(float2*)(out + (size_t)i * 2) = make_float2(base.x + a0, base.y + a1);
  }
  if (i == 0) {
    out[2 * M + 0] = -(accs[0] + accs[1]) * invP;
    out[2 * M + 1] = c1[0];
    out[2 * M + 2] = c2[0];
  }
}

extern "C" void kernel_launch(void* const* d_in, const int* in_sizes, int n_in,
                              void* d_out, int out_size, void* d_ws, size_t ws_size,
                              hipStream_t stream)
{
  const float* x   = (const float*)d_in[0];
  const int*   ei  = (const int*)d_in[1];
  const int*   ep  = (const int*)d_in[2];
  const int*   en  = (const int*)d_in[3];
  const float* W1  = (const float*)d_in[4];
  const float* b1  = (const float*)d_in[5];
  const float* W2  = (const float*)d_in[6];
  const float* b2  = (const float*)d_in[7];
  const float* W3  = (const float*)d_in[8];
  const float* b3  = (const float*)d_in[9];
  const float* l1W = (const float*)d_in[10];
  const float* l1b = (const float*)d_in[11];
  const float* l2W = (const float*)d_in[12];
  const float* l2b = (const float*)d_in[13];
  const float* c1  = (const float*)d_in[14];
  const float* c2  = (const float*)d_in[15];
  float* out = (float*)d_out;

  const int M = in_sizes[0] / 128;  // 50000
  const int E = in_sizes[1] / 2;    // 800000
  const int P = in_sizes[2] / 2;    // 400000
  const int* src = ei;
  const int* dst = ei + E;
  const int nb_scan = (M + 255) / 256;

  float* ws = (float*)d_ws;
  size_t o = 0;
  float*    dinv = ws + o;            o += 50176;
  int*      cnt  = (int*)(ws + o);    o += (size_t)M;
  int*      ptr  = (int*)(ws + o);    o += (size_t)M + 8;
  int*      cur  = (int*)(ws + o);    o += (size_t)M;
  int*      bsum = (int*)(ws + o);    o += 256;
  int*      csr_s = (int*)(ws + o);   o += (size_t)E;
  float*    csr_w = ws + o;           o += (size_t)E;
  ushort_t* xb   = (ushort_t*)(ws + o); o += (size_t)M * 64;
  ushort_t* tx0b = (ushort_t*)(ws + o); o += (size_t)M * 64;
  ushort_t* W1t  = (ushort_t*)(ws + o); o += 40960;
  ushort_t* W2t  = (ushort_t*)(ws + o); o += 35840;
  ushort_t* Wlt  = (ushort_t*)(ws + o); o += 14336;
  ushort_t* h    = (ushort_t*)(ws + o); o += (size_t)M * 160;
  float*    Ar   = ws + o;            o += (size_t)M * 100;   // conv2[0]+b2 -> x1 (in place)
  ushort_t* Brh  = (ushort_t*)(ws + o); o += (size_t)M * 50;
  float*    x2   = ws + o;            o += (size_t)M * 100;
  ushort_t* zh   = (ushort_t*)(ws + o); o += (size_t)M * 50;
  float*    t0   = ws + o;            o += (size_t)M * 2;
  float*    t1   = ws + o;            o += (size_t)M * 2;
  float*    accs = ws + o;            o += 8;

  hipMemsetAsync(dinv, 0, (size_t)M * 4, stream);
  hipMemsetAsync(cnt,  0, (size_t)M * 4, stream);
  hipMemsetAsync(accs, 0, 2 * 4, stream);

  // packing (independent, early)
  cvt_x_kernel<<<(M * 128 + 255) / 256, 256, 0, stream>>>(x, xb, M * 128);
  pack_w1<<<(320 * 256 + 255) / 256, 256, 0, stream>>>(W1, W1t);
  pack_w2<<<(224 * 320 + 255) / 256, 256, 0, stream>>>(W2, W2t);
  pack_wl<<<(224 * 128 + 255) / 256, 256, 0, stream>>>(l1W, l2W, Wlt);

  // CSR build
  deg_count_kernel<<<(E + 255) / 256, 256, 0, stream>>>(src, dst, dinv, cnt, E);
  dinv_kernel<<<(M + 255) / 256, 256, 0, stream>>>(dinv, M);
  scan_local<<<nb_scan, 256, 0, stream>>>(cnt, ptr, bsum, M);
  scan_bsum<<<1, 256, 0, stream>>>(bsum, nb_scan);
  scan_add<<<nb_scan, 256, 0, stream>>>(ptr, bsum, M, E);
  hipMemcpyAsync(cur, ptr, (size_t)M * 4, hipMemcpyDeviceToDevice, stream);
  fill_csr<<<(E + 255) / 256, 256, 0, stream>>>(src, dst, dinv, cur, csr_s, csr_w, E);

  const int gB = (M + 63) / 64;

  // conv1
  gather128h<<<(M * 64 + 255) / 256, 256, 0, stream>>>(xb, tx0b, ptr, csr_s, csr_w, M);
  gemm_mfma<0, 320, 256><<<gB, 256, 0, stream>>>(xb, tx0b, W1t, b1, nullptr, nullptr, h, nullptr, M);

  // conv2 (propagate after GEMM at 100)
  gemm_mfma<1, 224, 320><<<gB, 256, 0, stream>>>(h, nullptr, W2t, b2, nullptr, nullptr, Ar, Brh, M);
  gather100_x1<<<(M * 64 + 255) / 256, 256, 0, stream>>>(Brh, Ar, ptr, csr_s, csr_w, M);

  // lins
  gemm_mfma<2, 224, 128><<<gB, 256, 0, stream>>>(xb, nullptr, Wlt, l1b, l2b, Ar /*x1*/, x2, zh, M);

  // loss
  loss_bf16<<<2048, 256, 0, stream>>>(zh, ep, en, P, accs);

  // conv3 (propagate after GEMM at 2) + final fused
  w3_kernel<<<(M + 255) / 256, 256, 0, stream>>>(x2, W3, b3, t0, t1, M);
  gather2_final<<<(M + 255) / 256, 256, 0, stream>>>(t1, t0, ptr, csr_s, csr_w,
                                                     accs, c1, c2, out, M, 1.0f / (float)P);
}

// Round 5
// 553.919 us; speedup vs baseline: 2.5827x; 1.0476x over previous
//
#include <hip/hip_runtime.h>
#include <math.h>

// MTGCN R4: quarter-wave (16-lane) gathers and loss -> 4x rows in flight per wave;
// w3/x2 fused into lins epilogue (shuffle-reduced t0/t1); merged packing.
// Strides: Ar/Brh 112, zh 104 (16B-aligned rows for dwordx4 quarter loads).

typedef unsigned short ushort_t;
typedef __attribute__((ext_vector_type(8))) __bf16 bf16x8;
typedef __attribute__((ext_vector_type(8))) short s16x8;
typedef __attribute__((ext_vector_type(4))) float f32x4;

__device__ __forceinline__ f32x4 mfma16x16x32(s16x8 a, s16x8 b, f32x4 c) {
  return __builtin_amdgcn_mfma_f32_16x16x32_bf16(
      __builtin_bit_cast(bf16x8, a), __builtin_bit_cast(bf16x8, b), c, 0, 0, 0);
}
__device__ __forceinline__ ushort_t f2bf(float f) {
  union { float f; unsigned u; } c; c.f = f;
  unsigned r = (c.u + 0x7FFFu + ((c.u >> 16) & 1u)) >> 16;
  return (ushort_t)r;
}
__device__ __forceinline__ float blo(unsigned u) {
  union { unsigned u; float f; } c; c.u = u << 16; return c.f;
}
__device__ __forceinline__ float bhi(unsigned u) {
  union { unsigned u; float f; } c; c.u = u & 0xffff0000u; return c.f;
}

// =======================================================================
// MFMA GEMM: block 64(M) x NT(N), 4 waves 2x2, wave tile 32 x NT/2.
// VAR 0: conv1  A=[xb|tx0b] K=256 -> h bf16 [M][320] relu+b1 (cols>=300 zero)
// VAR 1: conv2  A=h [M][320] -> Ar fp32 stride112 (+b2, col<100), Brh bf16 stride112
// VAR 2: lins   A=xb [M][128] -> zh bf16 stride104 = x1+relu(+l2b);
//               x2=x1+relu(+l1b) folded into t0/t1 = x2@W3[k]+... via shuffle reduce
// =======================================================================
template<int VAR, int NT, int KTOT>
__global__ __launch_bounds__(256) void gemm_mfma(
    const ushort_t* __restrict__ A0, const ushort_t* __restrict__ A1,
    const ushort_t* __restrict__ Wt,
    const float* __restrict__ bias0, const float* __restrict__ bias1,
    const float* __restrict__ x1,
    const float* __restrict__ W3c, const float* __restrict__ b3c,
    void* __restrict__ out0, void* __restrict__ out1,
    float* __restrict__ t0g, float* __restrict__ t1g, int M)
{
  constexpr int NF = NT / 32;
  __shared__ __align__(16) ushort_t As[64 * 40];
  __shared__ __align__(16) ushort_t Bs[NT * 40];
  __shared__ float w3s[400];
  const int tid  = threadIdx.x;
  const int lane = tid & 63, w = tid >> 6;
  const int m0 = blockIdx.x * 64;
  const int wm = (w & 1) * 32, wn = (w >> 1) * (NT / 2);
  if (VAR == 2) { for (int i = tid; i < 400; i += 256) w3s[i] = W3c[i]; }
  f32x4 acc[2][NF];
#pragma unroll
  for (int i = 0; i < 2; ++i)
#pragma unroll
    for (int j = 0; j < NF; ++j) acc[i][j] = (f32x4){0.f, 0.f, 0.f, 0.f};

  for (int k0 = 0; k0 < KTOT; k0 += 32) {
    { // A stage
      const int r = tid >> 2, c8 = (tid & 3) * 8;
      const int gm = m0 + r;
      uint4 v = {0u, 0u, 0u, 0u};
      if (gm < M) {
        const ushort_t* src;
        if (VAR == 0) src = (k0 < 128) ? A0 + (size_t)gm * 128 + k0 + c8
                                       : A1 + (size_t)gm * 128 + (k0 - 128) + c8;
        else if (VAR == 1) src = A0 + (size_t)gm * 320 + k0 + c8;
        else src = A0 + (size_t)gm * 128 + k0 + c8;
        v = *(const uint4*)src;
      }
      *(uint4*)&As[r * 40 + c8] = v;
    }
    { // B stage
      const int c8 = (tid & 3) * 8;
#pragma unroll
      for (int i = 0; i < (NT * 4 + 255) / 256; ++i) {
        const int r = (tid >> 2) + i * 64;
        if (r < NT)
          *(uint4*)&Bs[r * 40 + c8] = *(const uint4*)(Wt + (size_t)r * KTOT + k0 + c8);
      }
    }
    __syncthreads();
    s16x8 af[2], bfr[NF];
#pragma unroll
    for (int mi = 0; mi < 2; ++mi)
      af[mi] = *(const s16x8*)&As[(wm + mi * 16 + (lane & 15)) * 40 + (lane >> 4) * 8];
#pragma unroll
    for (int ni = 0; ni < NF; ++ni)
      bfr[ni] = *(const s16x8*)&Bs[(wn + ni * 16 + (lane & 15)) * 40 + (lane >> 4) * 8];
#pragma unroll
    for (int mi = 0; mi < 2; ++mi)
#pragma unroll
      for (int ni = 0; ni < NF; ++ni)
        acc[mi][ni] = mfma16x16x32(af[mi], bfr[ni], acc[mi][ni]);
    __syncthreads();
  }

  if (VAR == 2) {
#pragma unroll
    for (int mi = 0; mi < 2; ++mi)
#pragma unroll
      for (int r = 0; r < 4; ++r) {
        const int gRow = m0 + wm + mi * 16 + ((lane >> 4) << 2) + r;
        float p0 = 0.f, p1 = 0.f, p2 = 0.f, p3 = 0.f;
#pragma unroll
        for (int ni = 0; ni < NF; ++ni) {
          const int col = wn + ni * 16 + (lane & 15);
          const float v = acc[mi][ni][r];
          if (gRow < M) {
            if (col < 100) {
              const float x2v = x1[(size_t)gRow * 112 + col] + fmaxf(v + bias0[col], 0.f);
              p0 = fmaf(x2v, w3s[col * 2 + 0], p0);
              p1 = fmaf(x2v, w3s[col * 2 + 1], p1);
              p2 = fmaf(x2v, w3s[200 + col * 2 + 0], p2);
              p3 = fmaf(x2v, w3s[200 + col * 2 + 1], p3);
            } else if (col < 200) {
              const int c = col - 100;
              ((ushort_t*)out1)[(size_t)gRow * 104 + c] =
                  f2bf(x1[(size_t)gRow * 112 + c] + fmaxf(v + bias1[c], 0.f));
            } else if (col < 204) {
              ((ushort_t*)out1)[(size_t)gRow * 104 + (col - 100)] = 0;
            }
          }
        }
        if (wn == 0) {  // only wn==0 waves hold cols<100
#pragma unroll
          for (int off = 8; off; off >>= 1) {
            p0 += __shfl_down(p0, off, 16);
            p1 += __shfl_down(p1, off, 16);
            p2 += __shfl_down(p2, off, 16);
            p3 += __shfl_down(p3, off, 16);
          }
          if ((lane & 15) == 0 && gRow < M) {
            t0g[(size_t)gRow * 2 + 0] = p0 + b3c[0];
            t0g[(size_t)gRow * 2 + 1] = p1 + b3c[1];
            t1g[(size_t)gRow * 2 + 0] = p2;
            t1g[(size_t)gRow * 2 + 1] = p3;
          }
        }
      }
  } else {
#pragma unroll
    for (int mi = 0; mi < 2; ++mi)
#pragma unroll
      for (int ni = 0; ni < NF; ++ni)
#pragma unroll
        for (int r = 0; r < 4; ++r) {
          const int gRow = m0 + wm + mi * 16 + ((lane >> 4) << 2) + r;
          const int col  = wn + ni * 16 + (lane & 15);
          if (gRow >= M) continue;
          const float v = acc[mi][ni][r];
          if (VAR == 0) {
            ushort_t* h = (ushort_t*)out0;
            h[(size_t)gRow * 320 + col] = (col < 300) ? f2bf(fmaxf(v + bias0[col], 0.f))
                                                      : (ushort_t)0;
          } else {
            if (col < 100) ((float*)out0)[(size_t)gRow * 112 + col] = v + bias0[col];
            else if (col < 200) ((ushort_t*)out1)[(size_t)gRow * 112 + (col - 100)] = f2bf(v);
          }
        }
  }
}

// ---------------- packing / conversion ----------------
__global__ void cvt_x_kernel(const float* __restrict__ x, ushort_t* __restrict__ xb, int n4) {
  const int i = blockIdx.x * 256 + threadIdx.x;
  if (i < n4) {
    const float4 v = ((const float4*)x)[i];
    ushort4 o; o.x = f2bf(v.x); o.y = f2bf(v.y); o.z = f2bf(v.z); o.w = f2bf(v.w);
    ((ushort4*)xb)[i] = o;
  }
}
__global__ void pack_all(const float* __restrict__ W1, const float* __restrict__ W2,
                         const float* __restrict__ l1W, const float* __restrict__ l2W,
                         ushort_t* __restrict__ W1t, ushort_t* __restrict__ W2t,
                         ushort_t* __restrict__ Wlt) {
  const int i = blockIdx.x * 256 + threadIdx.x;
  if (i < 81920) {                       // W1t [320][256]
    const int n = i >> 8, k = i & 255;
    float v = 0.f;
    if (n < 300) v = (k < 128) ? W1[k * 300 + n] : W1[38400 + (k - 128) * 300 + n];
    W1t[i] = f2bf(v);
  } else if (i < 153600) {               // W2t [224][320]
    const int j = i - 81920;
    const int n = j / 320, k = j - n * 320;
    float v = 0.f;
    if (n < 200 && k < 300) v = W2[(n < 100 ? 0 : 30000) + k * 100 + (n % 100)];
    W2t[j] = f2bf(v);
  } else if (i < 182272) {               // Wlt [224][128]
    const int j = i - 153600;
    const int n = j >> 7, k = j & 127;
    float v = 0.f;
    if (n < 100) v = l1W[n * 128 + k];
    else if (n < 200) v = l2W[(n - 100) * 128 + k];
    Wlt[j] = f2bf(v);
  }
}

// ---------------- degree + in-count, dinv
__global__ void deg_count_kernel(const int* __restrict__ src, const int* __restrict__ dst,
                                 float* __restrict__ deg, int* __restrict__ cnt, int E)
{
  const int e = blockIdx.x * blockDim.x + threadIdx.x;
  if (e < E) { atomicAdd(deg + src[e], 1.0f); atomicAdd(cnt + dst[e], 1); }
}
__global__ void dinv_kernel(float* __restrict__ d, int n) {
  const int i = blockIdx.x * blockDim.x + threadIdx.x;
  if (i < n) { const float v = d[i]; d[i] = (v > 0.f) ? 1.f / sqrtf(v) : 0.f; }
}

// ---------------- CSR build
__global__ void scan_local(const int* __restrict__ cnt, int* __restrict__ ptr,
                           int* __restrict__ bsum, int n)
{
  __shared__ int tmp[256];
  const int i = blockIdx.x * 256 + threadIdx.x;
  const int v = (i < n) ? cnt[i] : 0;
  tmp[threadIdx.x] = v;
  __syncthreads();
  for (int off = 1; off < 256; off <<= 1) {
    const int t = (threadIdx.x >= off) ? tmp[threadIdx.x - off] : 0;
    __syncthreads();
    tmp[threadIdx.x] += t;
    __syncthreads();
  }
  if (i < n) ptr[i] = tmp[threadIdx.x] - v;
  if (threadIdx.x == 255) bsum[blockIdx.x] = tmp[255];
}
__global__ void scan_bsum(int* __restrict__ bsum, int nb) {
  __shared__ int tmp[256];
  const int v = (threadIdx.x < nb) ? bsum[threadIdx.x] : 0;
  tmp[threadIdx.x] = v;
  __syncthreads();
  for (int off = 1; off < 256; off <<= 1) {
    const int t = (threadIdx.x >= off) ? tmp[threadIdx.x - off] : 0;
    __syncthreads();
    tmp[threadIdx.x] += t;
    __syncthreads();
  }
  if (threadIdx.x < nb) bsum[threadIdx.x] = tmp[threadIdx.x] - v;
}
__global__ void scan_add(int* __restrict__ ptr, const int* __restrict__ bsum, int n, int E) {
  const int i = blockIdx.x * 256 + threadIdx.x;
  if (i < n) ptr[i] += bsum[blockIdx.x];
  if (i == 0) ptr[n] = E;
}
__global__ void fill_csr(const int* __restrict__ src, const int* __restrict__ dst,
                         const float* __restrict__ dinv, int* __restrict__ cur,
                         int* __restrict__ cs, float* __restrict__ cw, int E)
{
  const int e = blockIdx.x * blockDim.x + threadIdx.x;
  if (e >= E) return;
  const int s = src[e], d = dst[e];
  const int pos = atomicAdd(cur + d, 1);
  cs[pos] = s;
  cw[pos] = -dinv[s] * dinv[d];
}

// ---------------- gather128: quarter-wave per node, dwordx4 lanes, 4-edge unroll
__global__ __launch_bounds__(256) void gather128q(
    const ushort_t* __restrict__ xb, ushort_t* __restrict__ txb,
    const int* __restrict__ ptr, const int* __restrict__ cs,
    const float* __restrict__ cw, int M)
{
  const int node = (blockIdx.x * 256 + threadIdx.x) >> 4;
  const int sub  = threadIdx.x & 15;
  if (node >= M) return;
  const int beg = ptr[node], end = ptr[node + 1];
  float a[8] = {0.f, 0.f, 0.f, 0.f, 0.f, 0.f, 0.f, 0.f};
  int p = beg;
  for (; p + 4 <= end; p += 4) {
    const int s0 = cs[p], s1 = cs[p + 1], s2 = cs[p + 2], s3 = cs[p + 3];
    const float w0 = cw[p], w1 = cw[p + 1], w2 = cw[p + 2], w3 = cw[p + 3];
    const uint4 v0 = *(const uint4*)(xb + (size_t)s0 * 128 + sub * 8);
    const uint4 v1 = *(const uint4*)(xb + (size_t)s1 * 128 + sub * 8);
    const uint4 v2 = *(const uint4*)(xb + (size_t)s2 * 128 + sub * 8);
    const uint4 v3 = *(const uint4*)(xb + (size_t)s3 * 128 + sub * 8);
#define ACC8(vv, ww) \
    a[0] = fmaf(ww, blo(vv.x), a[0]); a[1] = fmaf(ww, bhi(vv.x), a[1]); \
    a[2] = fmaf(ww, blo(vv.y), a[2]); a[3] = fmaf(ww, bhi(vv.y), a[3]); \
    a[4] = fmaf(ww, blo(vv.z), a[4]); a[5] = fmaf(ww, bhi(vv.z), a[5]); \
    a[6] = fmaf(ww, blo(vv.w), a[6]); a[7] = fmaf(ww, bhi(vv.w), a[7]);
    ACC8(v0, w0) ACC8(v1, w1) ACC8(v2, w2) ACC8(v3, w3)
  }
  for (; p < end; ++p) {
    const int s = cs[p]; const float w = cw[p];
    const uint4 v = *(const uint4*)(xb + (size_t)s * 128 + sub * 8);
    ACC8(v, w)
  }
  uint4 o;
  o.x = (unsigned)f2bf(a[0]) | ((unsigned)f2bf(a[1]) << 16);
  o.y = (unsigned)f2bf(a[2]) | ((unsigned)f2bf(a[3]) << 16);
  o.z = (unsigned)f2bf(a[4]) | ((unsigned)f2bf(a[5]) << 16);
  o.w = (unsigned)f2bf(a[6]) | ((unsigned)f2bf(a[7]) << 16);
  *(uint4*)(txb + (size_t)node * 128 + sub * 8) = o;
}

// ---------------- fused gather100 + x1 (quarter-wave, Brh/Ar stride 112)
__global__ __launch_bounds__(256) void gather100q_x1(
    const ushort_t* __restrict__ Brh, float* __restrict__ Ar,
    const int* __restrict__ ptr, const int* __restrict__ cs,
    const float* __restrict__ cw, int M)
{
  const int node = (blockIdx.x * 256 + threadIdx.x) >> 4;
  const int sub  = threadIdx.x & 15;
  if (node >= M) return;
  const int beg = ptr[node], end = ptr[node + 1];
  const bool act = sub < 14;
  float a[8] = {0.f, 0.f, 0.f, 0.f, 0.f, 0.f, 0.f, 0.f};
  int p = beg;
  for (; p + 4 <= end; p += 4) {
    const int s0 = cs[p], s1 = cs[p + 1], s2 = cs[p + 2], s3 = cs[p + 3];
    const float w0 = cw[p], w1 = cw[p + 1], w2 = cw[p + 2], w3 = cw[p + 3];
    if (act) {
      const uint4 v0 = *(const uint4*)(Brh + (size_t)s0 * 112 + sub * 8);
      const uint4 v1 = *(const uint4*)(Brh + (size_t)s1 * 112 + sub * 8);
      const uint4 v2 = *(const uint4*)(Brh + (size_t)s2 * 112 + sub * 8);
      const uint4 v3 = *(const uint4*)(Brh + (size_t)s3 * 112 + sub * 8);
      ACC8(v0, w0) ACC8(v1, w1) ACC8(v2, w2) ACC8(v3, w3)
    }
  }
  for (; p < end; ++p) {
    const int s = cs[p]; const float w = cw[p];
    if (act) {
      const uint4 v = *(const uint4*)(Brh + (size_t)s * 112 + sub * 8);
      ACC8(v, w)
    }
  }
  if (act) {
    float* dstp = Ar + (size_t)node * 112 + sub * 8;
    const float4 b0 = *(const float4*)dstp;
    const float4 b1 = *(const float4*)(dstp + 4);
    *(float4*)dstp = make_float4(fmaxf(b0.x + a[0], 0.f), fmaxf(b0.y + a[1], 0.f),
                                 fmaxf(b0.z + a[2], 0.f), fmaxf(b0.w + a[3], 0.f));
    *(float4*)(dstp + 4) = make_float4(fmaxf(b1.x + a[4], 0.f), fmaxf(b1.y + a[5], 0.f),
                                       fmaxf(b1.z + a[6], 0.f), fmaxf(b1.w + a[7], 0.f));
  }
}
#undef ACC8

// ---------------- loss: quarter-wave per pair (zh stride 104 = 13x16B), 2-way ILP
__global__ __launch_bounds__(256) void loss_bf16(
    const ushort_t* __restrict__ zh, const int* __restrict__ ep,
    const int* __restrict__ en, int P, float* __restrict__ acc)
{
  __shared__ float red[8];
  const int tid = threadIdx.x;
  const int lane = tid & 63, wib = tid >> 6;
  const int sub = lane & 15;
  const int slot0 = blockIdx.x * 16 + (tid >> 4);
  const int step = gridDim.x * 16;
  const bool act = sub < 13;
  float tp = 0.f, tn = 0.f;

#define DOT16(sv, ua, ub) \
  sv = fmaf(blo(ua.x), blo(ub.x), sv); sv = fmaf(bhi(ua.x), bhi(ub.x), sv); \
  sv = fmaf(blo(ua.y), blo(ub.y), sv); sv = fmaf(bhi(ua.y), bhi(ub.y), sv); \
  sv = fmaf(blo(ua.z), blo(ub.z), sv); sv = fmaf(bhi(ua.z), bhi(ub.z), sv); \
  sv = fmaf(blo(ua.w), blo(ub.w), sv); sv = fmaf(bhi(ua.w), bhi(ub.w), sv);

  int g = slot0;
  for (; g + step < 2 * P; g += 2 * step) {
    const int gA = g, gB = g + step;
    const int negA = (gA >= P), negB = (gB >= P);
    const int pA = negA ? gA - P : gA, pB = negB ? gB - P : gB;
    const int* iA = negA ? en : ep;
    const int* iB = negB ? en : ep;
    const int naA = iA[pA], nbA = iA[P + pA];
    const int naB = iB[pB], nbB = iB[P + pB];
    float sA = 0.f, sB = 0.f;
    if (act) {
      const uint4 a1 = *(const uint4*)(zh + (size_t)naA * 104 + sub * 8);
      const uint4 b1 = *(const uint4*)(zh + (size_t)nbA * 104 + sub * 8);
      const uint4 a2 = *(const uint4*)(zh + (size_t)naB * 104 + sub * 8);
      const uint4 b2 = *(const uint4*)(zh + (size_t)nbB * 104 + sub * 8);
      DOT16(sA, a1, b1)
      DOT16(sB, a2, b2)
    }
#pragma unroll
    for (int off = 8; off; off >>= 1) {
      sA += __shfl_down(sA, off, 16);
      sB += __shfl_down(sB, off, 16);
    }
    if (sub == 0) {
      const float gA_ = 1.f / (1.f + expf(-sA));
      if (negA) tn += logf(1.f - gA_ + 1e-15f); else tp += logf(gA_ + 1e-15f);
      const float gB_ = 1.f / (1.f + expf(-sB));
      if (negB) tn += logf(1.f - gB_ + 1e-15f); else tp += logf(gB_ + 1e-15f);
    }
  }
  if (g < 2 * P) {
    const int neg = (g >= P);
    const int p = neg ? g - P : g;
    const int* ia = neg ? en : ep;
    const int na = ia[p], nb = ia[P + p];
    float s = 0.f;
    if (act) {
      const uint4 a = *(const uint4*)(zh + (size_t)na * 104 + sub * 8);
      const uint4 b = *(const uint4*)(zh + (size_t)nb * 104 + sub * 8);
      DOT16(s, a, b)
    }
#pragma unroll
    for (int off = 8; off; off >>= 1) s += __shfl_down(s, off, 16);
    if (sub == 0) {
      const float sig = 1.f / (1.f + expf(-s));
      if (neg) tn += logf(1.f - sig + 1e-15f); else tp += logf(sig + 1e-15f);
    }
  }
#undef DOT16
  // combine 4 quarters -> lane 0 of wave
  tp += __shfl_down(tp, 32, 64); tn += __shfl_down(tn, 32, 64);
  tp += __shfl_down(tp, 16, 64); tn += __shfl_down(tn, 16, 64);
  if (lane == 0) { red[wib] = tp; red[4 + wib] = tn; }
  __syncthreads();
  if (tid == 0) {
    atomicAdd(acc + 0, red[0] + red[1] + red[2] + red[3]);
    atomicAdd(acc + 1, red[4] + red[5] + red[6] + red[7]);
  }
}

// ---------------- fused gather2 + final
__global__ void gather2_final(
    const float* __restrict__ t1, const float* __restrict__ t0,
    const int* __restrict__ ptr, const int* __restrict__ cs,
    const float* __restrict__ cw, const float* __restrict__ accs,
    const float* __restrict__ c1, const float* __restrict__ c2,
    float* __restrict__ out, int M, float invP)
{
  const int i = blockIdx.x * blockDim.x + threadIdx.x;
  if (i < M) {
    float a0 = 0.f, a1 = 0.f;
    const int beg = ptr[i], end = ptr[i + 1];
    int p = beg;
    for (; p + 4 <= end; p += 4) {
      const int s0 = cs[p], s1 = cs[p + 1], s2 = cs[p + 2], s3 = cs[p + 3];
      const float w0 = cw[p], w1 = cw[p + 1], w2 = cw[p + 2], w3 = cw[p + 3];
      const float2 v0 = *(const float2*)(t1 + (size_t)s0 * 2);
      const float2 v1 = *(const float2*)(t1 + (size_t)s1 * 2);
      const float2 v2 = *(const float2*)(t1 + (size_t)s2 * 2);
      const float2 v3 = *(const float2*)(t1 + (size_t)s3 * 2);
      a0 = fmaf(w0, v0.x, a0); a1 = fmaf(w0, v0.y, a1);
      a0 = fmaf(w1, v1.x, a0); a1 = fmaf(w1, v1.y, a1);
      a0 = fmaf(w2, v2.x, a0); a1 = fmaf(w2, v2.y, a1);
      a0 = fmaf(w3, v3.x, a0); a1 = fmaf(w3, v3.y, a1);
    }
    for (; p < end; ++p) {
      const int s = cs[p]; const float w = cw[p];
      const float2 v = *(const float2*)(t1 + (size_t)s * 2);
      a0 = fmaf(w, v.x, a0); a1 = fmaf(w, v.y, a1);
    }
    const float2 base = *(const float2*)(t0 + (size_t)i * 2);
    *(float2*)(out + (size_t)i * 2) = make_float2(base.x + a0, base.y + a1);
  }
  if (i == 0) {
    out[2 * M + 0] = -(accs[0] + accs[1]) * invP;
    out[2 * M + 1] = c1[0];
    out[2 * M + 2] = c2[0];
  }
}

extern "C" void kernel_launch(void* const* d_in, const int* in_sizes, int n_in,
                              void* d_out, int out_size, void* d_ws, size_t ws_size,
                              hipStream_t stream)
{
  const float* x   = (const float*)d_in[0];
  const int*   ei  = (const int*)d_in[1];
  const int*   ep  = (const int*)d_in[2];
  const int*   en  = (const int*)d_in[3];
  const float* W1  = (const float*)d_in[4];
  const float* b1  = (const float*)d_in[5];
  const float* W2  = (const float*)d_in[6];
  const float* b2  = (const float*)d_in[7];
  const float* W3  = (const float*)d_in[8];
  const float* b3  = (const float*)d_in[9];
  const float* l1W = (const float*)d_in[10];
  const float* l1b = (const float*)d_in[11];
  const float* l2W = (const float*)d_in[12];
  const float* l2b = (const float*)d_in[13];
  const float* c1  = (const float*)d_in[14];
  const float* c2  = (const float*)d_in[15];
  float* out = (float*)d_out;

  const int M = in_sizes[0] / 128;  // 50000
  const int E = in_sizes[1] / 2;    // 800000
  const int P = in_sizes[2] / 2;    // 400000
  const int* src = ei;
  const int* dst = ei + E;
  const int nb_scan = (M + 255) / 256;

  float* ws = (float*)d_ws;
  size_t o = 0;
  float*    dinv = ws + o;            o += 50176;
  int*      cnt  = (int*)(ws + o);    o += (size_t)M;
  int*      ptr  = (int*)(ws + o);    o += (size_t)M + 8;
  int*      cur  = (int*)(ws + o);    o += (size_t)M;
  int*      bsum = (int*)(ws + o);    o += 256;
  int*      csr_s = (int*)(ws + o);   o += (size_t)E;
  float*    csr_w = ws + o;           o += (size_t)E;
  ushort_t* xb   = (ushort_t*)(ws + o); o += (size_t)M * 64;   // [M][128]
  ushort_t* tx0b = (ushort_t*)(ws + o); o += (size_t)M * 64;   // [M][128]
  ushort_t* W1t  = (ushort_t*)(ws + o); o += 40960;            // [320][256]
  ushort_t* W2t  = (ushort_t*)(ws + o); o += 35840;            // [224][320]
  ushort_t* Wlt  = (ushort_t*)(ws + o); o += 14336;            // [224][128]
  ushort_t* h    = (ushort_t*)(ws + o); o += (size_t)M * 160;  // [M][320]
  float*    Ar   = ws + o;            o += (size_t)M * 112;    // stride 112 -> x1
  ushort_t* Brh  = (ushort_t*)(ws + o); o += (size_t)M * 56;   // [M][112] bf16
  ushort_t* zh   = (ushort_t*)(ws + o); o += (size_t)M * 52;   // [M][104] bf16
  float*    t0   = ws + o;            o += (size_t)M * 2;
  float*    t1   = ws + o;            o += (size_t)M * 2;
  float*    accs = ws + o;            o += 8;

  hipMemsetAsync(dinv, 0, (size_t)M * 4, stream);
  hipMemsetAsync(cnt,  0, (size_t)M * 4, stream);
  hipMemsetAsync(accs, 0, 2 * 4, stream);

  // packing (independent, early)
  cvt_x_kernel<<<(M * 32 + 255) / 256, 256, 0, stream>>>(x, xb, M * 32);
  pack_all<<<(182272 + 255) / 256, 256, 0, stream>>>(W1, W2, l1W, l2W, W1t, W2t, Wlt);

  // CSR build
  deg_count_kernel<<<(E + 255) / 256, 256, 0, stream>>>(src, dst, dinv, cnt, E);
  dinv_kernel<<<(M + 255) / 256, 256, 0, stream>>>(dinv, M);
  scan_local<<<nb_scan, 256, 0, stream>>>(cnt, ptr, bsum, M);
  scan_bsum<<<1, 256, 0, stream>>>(bsum, nb_scan);
  scan_add<<<nb_scan, 256, 0, stream>>>(ptr, bsum, M, E);
  hipMemcpyAsync(cur, ptr, (size_t)M * 4, hipMemcpyDeviceToDevice, stream);
  fill_csr<<<(E + 255) / 256, 256, 0, stream>>>(src, dst, dinv, cur, csr_s, csr_w, E);

  const int gB = (M + 63) / 64;
  const int gQ = (M * 16 + 255) / 256;

  // conv1
  gather128q<<<gQ, 256, 0, stream>>>(xb, tx0b, ptr, csr_s, csr_w, M);
  gemm_mfma<0, 320, 256><<<gB, 256, 0, stream>>>(
      xb, tx0b, W1t, b1, nullptr, nullptr, nullptr, nullptr, h, nullptr, nullptr, nullptr, M);

  // conv2 (propagate after GEMM at 100)
  gemm_mfma<1, 224, 320><<<gB, 256, 0, stream>>>(
      h, nullptr, W2t, b2, nullptr, nullptr, nullptr, nullptr, Ar, Brh, nullptr, nullptr, M);
  gather100q_x1<<<gQ, 256, 0, stream>>>(Brh, Ar, ptr, csr_s, csr_w, M);

  // lins + fused w3 (x2 never materialized)
  gemm_mfma<2, 224, 128><<<gB, 256, 0, stream>>>(
      xb, nullptr, Wlt, l1b, l2b, Ar /*x1*/, W3, b3, nullptr, zh, t0, t1, M);

  // loss
  loss_bf16<<<2048, 256, 0, stream>>>(zh, ep, en, P, accs);

  // conv3 propagation + final
  gather2_final<<<(M + 255) / 256, 256, 0, stream>>>(t1, t0, ptr, csr_s, csr_w,
                                                     accs, c1, c2, out, M, 1.0f / (float)P);
}

// Round 7
// 532.895 us; speedup vs baseline: 2.6846x; 1.0395x over previous
//
#include <hip/hip_runtime.h>
#include <math.h>

// MTGCN R5b: fp8 (OCP e4m3 via HW cvt builtins, self-consistent encode/decode) for
// all random-row-read paths: gather128 input xf8, gather100 input Brh, loss input zf8.
// All fp8 rows are 128B line-aligned (1 cache line per row). Eighth-wave (8-lane)
// gathers/loss: 8 rows per wave instruction, 4-deep unroll -> 32 rows in flight.
// GEMMs stay bf16 MFMA. Ar/x1 restrided to 128 floats.
// (R5 fix: macro param renamed w->ww; `u.w` was being substituted.)

typedef unsigned short ushort_t;
typedef unsigned char u8;
typedef __attribute__((ext_vector_type(8))) __bf16 bf16x8;
typedef __attribute__((ext_vector_type(8))) short s16x8;
typedef __attribute__((ext_vector_type(4))) float f32x4;
typedef __attribute__((ext_vector_type(2))) float f32x2;

__device__ __forceinline__ f32x4 mfma16x16x32(s16x8 a, s16x8 b, f32x4 c) {
  return __builtin_amdgcn_mfma_f32_16x16x32_bf16(
      __builtin_bit_cast(bf16x8, a), __builtin_bit_cast(bf16x8, b), c, 0, 0, 0);
}
__device__ __forceinline__ ushort_t f2bf(float f) {
  union { float f; unsigned u; } c; c.f = f;
  unsigned r = (c.u + 0x7FFFu + ((c.u >> 16) & 1u)) >> 16;
  return (ushort_t)r;
}
__device__ __forceinline__ float blo(unsigned u) {
  union { unsigned u; float f; } c; c.u = u << 16; return c.f;
}
__device__ __forceinline__ float bhi(unsigned u) {
  union { unsigned u; float f; } c; c.u = u & 0xffff0000u; return c.f;
}
__device__ __forceinline__ f32x2 cvt2lo(unsigned u) {
  return __builtin_amdgcn_cvt_pk_f32_fp8((int)u, false);
}
__device__ __forceinline__ f32x2 cvt2hi(unsigned u) {
  return __builtin_amdgcn_cvt_pk_f32_fp8((int)u, true);
}
__device__ __forceinline__ u8 f2fp8(float f) {
  return (u8)(__builtin_amdgcn_cvt_pk_fp8_f32(f, 0.f, 0, false) & 0xff);
}

// =======================================================================
// MFMA GEMM: block 64(M) x NT(N), 4 waves 2x2, wave tile 32 x NT/2.
// VAR 0: conv1  A=[xb|tx0b] K=256 -> h bf16 [M][320] relu+b1 (cols>=300 zero)
// VAR 1: conv2  A=h [M][320] -> Ar fp32 stride128 (+b2, col<100), Brh fp8 stride128
// VAR 2: lins   A=xb [M][128] -> zf8 fp8 stride128 = x1+relu(+l2b);
//               x2=x1+relu(+l1b) folded into t0/t1 via w3 shuffle reduce
// =======================================================================
template<int VAR, int NT, int KTOT>
__global__ __launch_bounds__(256) void gemm_mfma(
    const ushort_t* __restrict__ A0, const ushort_t* __restrict__ A1,
    const ushort_t* __restrict__ Wt,
    const float* __restrict__ bias0, const float* __restrict__ bias1,
    const float* __restrict__ x1,
    const float* __restrict__ W3c, const float* __restrict__ b3c,
    void* __restrict__ out0, void* __restrict__ out1,
    float* __restrict__ t0g, float* __restrict__ t1g, int M)
{
  constexpr int NF = NT / 32;
  __shared__ __align__(16) ushort_t As[64 * 40];
  __shared__ __align__(16) ushort_t Bs[NT * 40];
  __shared__ float w3s[400];
  const int tid  = threadIdx.x;
  const int lane = tid & 63, w = tid >> 6;
  const int m0 = blockIdx.x * 64;
  const int wm = (w & 1) * 32, wn = (w >> 1) * (NT / 2);
  if (VAR == 2) { for (int i = tid; i < 400; i += 256) w3s[i] = W3c[i]; }
  f32x4 acc[2][NF];
#pragma unroll
  for (int i = 0; i < 2; ++i)
#pragma unroll
    for (int j = 0; j < NF; ++j) acc[i][j] = (f32x4){0.f, 0.f, 0.f, 0.f};

  for (int k0 = 0; k0 < KTOT; k0 += 32) {
    { // A stage
      const int r = tid >> 2, c8 = (tid & 3) * 8;
      const int gm = m0 + r;
      uint4 v = {0u, 0u, 0u, 0u};
      if (gm < M) {
        const ushort_t* srcp;
        if (VAR == 0) srcp = (k0 < 128) ? A0 + (size_t)gm * 128 + k0 + c8
                                        : A1 + (size_t)gm * 128 + (k0 - 128) + c8;
        else if (VAR == 1) srcp = A0 + (size_t)gm * 320 + k0 + c8;
        else srcp = A0 + (size_t)gm * 128 + k0 + c8;
        v = *(const uint4*)srcp;
      }
      *(uint4*)&As[r * 40 + c8] = v;
    }
    { // B stage
      const int c8 = (tid & 3) * 8;
#pragma unroll
      for (int i = 0; i < (NT * 4 + 255) / 256; ++i) {
        const int r = (tid >> 2) + i * 64;
        if (r < NT)
          *(uint4*)&Bs[r * 40 + c8] = *(const uint4*)(Wt + (size_t)r * KTOT + k0 + c8);
      }
    }
    __syncthreads();
    s16x8 af[2], bfr[NF];
#pragma unroll
    for (int mi = 0; mi < 2; ++mi)
      af[mi] = *(const s16x8*)&As[(wm + mi * 16 + (lane & 15)) * 40 + (lane >> 4) * 8];
#pragma unroll
    for (int ni = 0; ni < NF; ++ni)
      bfr[ni] = *(const s16x8*)&Bs[(wn + ni * 16 + (lane & 15)) * 40 + (lane >> 4) * 8];
#pragma unroll
    for (int mi = 0; mi < 2; ++mi)
#pragma unroll
      for (int ni = 0; ni < NF; ++ni)
        acc[mi][ni] = mfma16x16x32(af[mi], bfr[ni], acc[mi][ni]);
    __syncthreads();
  }

  if (VAR == 2) {
#pragma unroll
    for (int mi = 0; mi < 2; ++mi)
#pragma unroll
      for (int r = 0; r < 4; ++r) {
        const int gRow = m0 + wm + mi * 16 + ((lane >> 4) << 2) + r;
        float p0 = 0.f, p1 = 0.f, p2 = 0.f, p3 = 0.f;
#pragma unroll
        for (int ni = 0; ni < NF; ++ni) {
          const int col = wn + ni * 16 + (lane & 15);
          const float v = acc[mi][ni][r];
          if (gRow < M) {
            if (col < 100) {
              const float x2v = x1[(size_t)gRow * 128 + col] + fmaxf(v + bias0[col], 0.f);
              p0 = fmaf(x2v, w3s[col * 2 + 0], p0);
              p1 = fmaf(x2v, w3s[col * 2 + 1], p1);
              p2 = fmaf(x2v, w3s[200 + col * 2 + 0], p2);
              p3 = fmaf(x2v, w3s[200 + col * 2 + 1], p3);
            } else if (col < 200) {
              const int c = col - 100;
              ((u8*)out1)[(size_t)gRow * 128 + c] =
                  f2fp8(x1[(size_t)gRow * 128 + c] + fmaxf(v + bias1[c], 0.f));
            }
          }
        }
        if (wn == 0) {
#pragma unroll
          for (int off = 8; off; off >>= 1) {
            p0 += __shfl_down(p0, off, 16);
            p1 += __shfl_down(p1, off, 16);
            p2 += __shfl_down(p2, off, 16);
            p3 += __shfl_down(p3, off, 16);
          }
          if ((lane & 15) == 0 && gRow < M) {
            t0g[(size_t)gRow * 2 + 0] = p0 + b3c[0];
            t0g[(size_t)gRow * 2 + 1] = p1 + b3c[1];
            t1g[(size_t)gRow * 2 + 0] = p2;
            t1g[(size_t)gRow * 2 + 1] = p3;
          }
        }
      }
  } else {
#pragma unroll
    for (int mi = 0; mi < 2; ++mi)
#pragma unroll
      for (int ni = 0; ni < NF; ++ni)
#pragma unroll
        for (int r = 0; r < 4; ++r) {
          const int gRow = m0 + wm + mi * 16 + ((lane >> 4) << 2) + r;
          const int col  = wn + ni * 16 + (lane & 15);
          if (gRow >= M) continue;
          const float v = acc[mi][ni][r];
          if (VAR == 0) {
            ushort_t* h = (ushort_t*)out0;
            h[(size_t)gRow * 320 + col] = (col < 300) ? f2bf(fmaxf(v + bias0[col], 0.f))
                                                      : (ushort_t)0;
          } else {
            if (col < 100) ((float*)out0)[(size_t)gRow * 128 + col] = v + bias0[col];
            else if (col < 200) ((u8*)out1)[(size_t)gRow * 128 + (col - 100)] = f2fp8(v);
          }
        }
  }
}

// ---------------- packing / conversion ----------------
__global__ void cvt_x_kernel(const float* __restrict__ x, ushort_t* __restrict__ xb,
                             u8* __restrict__ xf8, int n4) {
  const int i = blockIdx.x * 256 + threadIdx.x;
  if (i < n4) {
    const float4 v = ((const float4*)x)[i];
    ushort4 o; o.x = f2bf(v.x); o.y = f2bf(v.y); o.z = f2bf(v.z); o.w = f2bf(v.w);
    ((ushort4*)xb)[i] = o;
    int p = 0;
    p = __builtin_amdgcn_cvt_pk_fp8_f32(v.x, v.y, p, false);
    p = __builtin_amdgcn_cvt_pk_fp8_f32(v.z, v.w, p, true);
    ((unsigned*)xf8)[i] = (unsigned)p;
  }
}
__global__ void pack_all(const float* __restrict__ W1, const float* __restrict__ W2,
                         const float* __restrict__ l1W, const float* __restrict__ l2W,
                         ushort_t* __restrict__ W1t, ushort_t* __restrict__ W2t,
                         ushort_t* __restrict__ Wlt) {
  const int i = blockIdx.x * 256 + threadIdx.x;
  if (i < 81920) {                       // W1t [320][256]
    const int n = i >> 8, k = i & 255;
    float v = 0.f;
    if (n < 300) v = (k < 128) ? W1[k * 300 + n] : W1[38400 + (k - 128) * 300 + n];
    W1t[i] = f2bf(v);
  } else if (i < 153600) {               // W2t [224][320]
    const int j = i - 81920;
    const int n = j / 320, k = j - n * 320;
    float v = 0.f;
    if (n < 200 && k < 300) v = W2[(n < 100 ? 0 : 30000) + k * 100 + (n % 100)];
    W2t[j] = f2bf(v);
  } else if (i < 182272) {               // Wlt [224][128]
    const int j = i - 153600;
    const int n = j >> 7, k = j & 127;
    float v = 0.f;
    if (n < 100) v = l1W[n * 128 + k];
    else if (n < 200) v = l2W[(n - 100) * 128 + k];
    Wlt[j] = f2bf(v);
  }
}

// ---------------- degree + in-count, dinv
__global__ void deg_count_kernel(const int* __restrict__ src, const int* __restrict__ dst,
                                 float* __restrict__ deg, int* __restrict__ cnt, int E)
{
  const int e = blockIdx.x * blockDim.x + threadIdx.x;
  if (e < E) { atomicAdd(deg + src[e], 1.0f); atomicAdd(cnt + dst[e], 1); }
}
__global__ void dinv_kernel(float* __restrict__ d, int n) {
  const int i = blockIdx.x * blockDim.x + threadIdx.x;
  if (i < n) { const float v = d[i]; d[i] = (v > 0.f) ? 1.f / sqrtf(v) : 0.f; }
}

// ---------------- CSR build
__global__ void scan_local(const int* __restrict__ cnt, int* __restrict__ ptr,
                           int* __restrict__ bsum, int n)
{
  __shared__ int tmp[256];
  const int i = blockIdx.x * 256 + threadIdx.x;
  const int v = (i < n) ? cnt[i] : 0;
  tmp[threadIdx.x] = v;
  __syncthreads();
  for (int off = 1; off < 256; off <<= 1) {
    const int t = (threadIdx.x >= off) ? tmp[threadIdx.x - off] : 0;
    __syncthreads();
    tmp[threadIdx.x] += t;
    __syncthreads();
  }
  if (i < n) ptr[i] = tmp[threadIdx.x] - v;
  if (threadIdx.x == 255) bsum[blockIdx.x] = tmp[255];
}
__global__ void scan_bsum(int* __restrict__ bsum, int nb) {
  __shared__ int tmp[256];
  const int v = (threadIdx.x < nb) ? bsum[threadIdx.x] : 0;
  tmp[threadIdx.x] = v;
  __syncthreads();
  for (int off = 1; off < 256; off <<= 1) {
    const int t = (threadIdx.x >= off) ? tmp[threadIdx.x - off] : 0;
    __syncthreads();
    tmp[threadIdx.x] += t;
    __syncthreads();
  }
  if (threadIdx.x < nb) bsum[threadIdx.x] = tmp[threadIdx.x] - v;
}
__global__ void scan_add(int* __restrict__ ptr, const int* __restrict__ bsum, int n, int E) {
  const int i = blockIdx.x * 256 + threadIdx.x;
  if (i < n) ptr[i] += bsum[blockIdx.x];
  if (i == 0) ptr[n] = E;
}
__global__ void fill_csr(const int* __restrict__ src, const int* __restrict__ dst,
                         const float* __restrict__ dinv, int* __restrict__ cur,
                         int* __restrict__ cs, float* __restrict__ cw, int E)
{
  const int e = blockIdx.x * blockDim.x + threadIdx.x;
  if (e >= E) return;
  const int s = src[e], d = dst[e];
  const int pos = atomicAdd(cur + d, 1);
  cs[pos] = s;
  cw[pos] = -dinv[s] * dinv[d];
}

// fp8 decode+accumulate: 16 fp8 (uint4) scaled by ww into a[0..15]
#define ACCV(u, ww) { f32x2 t; \
  t = cvt2lo(u.x); a[0]  = fmaf(ww, t.x, a[0]);  a[1]  = fmaf(ww, t.y, a[1]);  \
  t = cvt2hi(u.x); a[2]  = fmaf(ww, t.x, a[2]);  a[3]  = fmaf(ww, t.y, a[3]);  \
  t = cvt2lo(u.y); a[4]  = fmaf(ww, t.x, a[4]);  a[5]  = fmaf(ww, t.y, a[5]);  \
  t = cvt2hi(u.y); a[6]  = fmaf(ww, t.x, a[6]);  a[7]  = fmaf(ww, t.y, a[7]);  \
  t = cvt2lo(u.z); a[8]  = fmaf(ww, t.x, a[8]);  a[9]  = fmaf(ww, t.y, a[9]);  \
  t = cvt2hi(u.z); a[10] = fmaf(ww, t.x, a[10]); a[11] = fmaf(ww, t.y, a[11]); \
  t = cvt2lo(u.w); a[12] = fmaf(ww, t.x, a[12]); a[13] = fmaf(ww, t.y, a[13]); \
  t = cvt2hi(u.w); a[14] = fmaf(ww, t.x, a[14]); a[15] = fmaf(ww, t.y, a[15]); }

// ---------------- gather128: eighth-wave (8 lanes x 16B = 128B row), 4-edge unroll
__global__ __launch_bounds__(256) void gather128e(
    const u8* __restrict__ xf8, ushort_t* __restrict__ txb,
    const int* __restrict__ ptr, const int* __restrict__ cs,
    const float* __restrict__ cw, int M)
{
  const int node = (blockIdx.x * 256 + threadIdx.x) >> 3;
  const int sub  = threadIdx.x & 7;
  if (node >= M) return;
  const int beg = ptr[node], end = ptr[node + 1];
  float a[16] = {};
  int p = beg;
  for (; p + 4 <= end; p += 4) {
    const int s0 = cs[p], s1 = cs[p + 1], s2 = cs[p + 2], s3 = cs[p + 3];
    const float w0 = cw[p], w1 = cw[p + 1], w2 = cw[p + 2], w3 = cw[p + 3];
    const uint4 v0 = *(const uint4*)(xf8 + (size_t)s0 * 128 + sub * 16);
    const uint4 v1 = *(const uint4*)(xf8 + (size_t)s1 * 128 + sub * 16);
    const uint4 v2 = *(const uint4*)(xf8 + (size_t)s2 * 128 + sub * 16);
    const uint4 v3 = *(const uint4*)(xf8 + (size_t)s3 * 128 + sub * 16);
    ACCV(v0, w0) ACCV(v1, w1) ACCV(v2, w2) ACCV(v3, w3)
  }
  for (; p < end; ++p) {
    const int s = cs[p]; const float wq = cw[p];
    const uint4 v = *(const uint4*)(xf8 + (size_t)s * 128 + sub * 16);
    ACCV(v, wq)
  }
  uint4 o1, o2;
  o1.x = (unsigned)f2bf(a[0])  | ((unsigned)f2bf(a[1])  << 16);
  o1.y = (unsigned)f2bf(a[2])  | ((unsigned)f2bf(a[3])  << 16);
  o1.z = (unsigned)f2bf(a[4])  | ((unsigned)f2bf(a[5])  << 16);
  o1.w = (unsigned)f2bf(a[6])  | ((unsigned)f2bf(a[7])  << 16);
  o2.x = (unsigned)f2bf(a[8])  | ((unsigned)f2bf(a[9])  << 16);
  o2.y = (unsigned)f2bf(a[10]) | ((unsigned)f2bf(a[11]) << 16);
  o2.z = (unsigned)f2bf(a[12]) | ((unsigned)f2bf(a[13]) << 16);
  o2.w = (unsigned)f2bf(a[14]) | ((unsigned)f2bf(a[15]) << 16);
  ushort_t* dstp = txb + (size_t)node * 128 + sub * 16;
  *(uint4*)dstp = o1;
  *(uint4*)(dstp + 8) = o2;
}

// ---------------- fused gather100 + x1 (eighth-wave, Brh fp8 stride 128B, Ar stride 128)
__global__ __launch_bounds__(256) void gather100e_x1(
    const u8* __restrict__ Brh, float* __restrict__ Ar,
    const int* __restrict__ ptr, const int* __restrict__ cs,
    const float* __restrict__ cw, int M)
{
  const int node = (blockIdx.x * 256 + threadIdx.x) >> 3;
  const int sub  = threadIdx.x & 7;
  if (node >= M) return;
  const int beg = ptr[node], end = ptr[node + 1];
  float a[16] = {};
  int p = beg;
  for (; p + 4 <= end; p += 4) {
    const int s0 = cs[p], s1 = cs[p + 1], s2 = cs[p + 2], s3 = cs[p + 3];
    const float w0 = cw[p], w1 = cw[p + 1], w2 = cw[p + 2], w3 = cw[p + 3];
    const uint4 v0 = *(const uint4*)(Brh + (size_t)s0 * 128 + sub * 16);
    const uint4 v1 = *(const uint4*)(Brh + (size_t)s1 * 128 + sub * 16);
    const uint4 v2 = *(const uint4*)(Brh + (size_t)s2 * 128 + sub * 16);
    const uint4 v3 = *(const uint4*)(Brh + (size_t)s3 * 128 + sub * 16);
    ACCV(v0, w0) ACCV(v1, w1) ACCV(v2, w2) ACCV(v3, w3)
  }
  for (; p < end; ++p) {
    const int s = cs[p]; const float wq = cw[p];
    const uint4 v = *(const uint4*)(Brh + (size_t)s * 128 + sub * 16);
    ACCV(v, wq)
  }
  // x1 = relu(Ar + tx) in place; cols >=100 hold garbage (never read)
  float* dstp = Ar + (size_t)node * 128 + sub * 16;
#pragma unroll
  for (int q = 0; q < 4; ++q) {
    float4 b = *(const float4*)(dstp + q * 4);
    b.x = fmaxf(b.x + a[q * 4 + 0], 0.f);
    b.y = fmaxf(b.y + a[q * 4 + 1], 0.f);
    b.z = fmaxf(b.z + a[q * 4 + 2], 0.f);
    b.w = fmaxf(b.w + a[q * 4 + 3], 0.f);
    *(float4*)(dstp + q * 4) = b;
  }
}
#undef ACCV

// ---------------- loss: eighth-wave per pair (zf8 stride 128B = 1 line), 2-way ILP
#define DOTV(uu, vv, s) { f32x2 p_, q_; \
  p_ = cvt2lo(uu.x); q_ = cvt2lo(vv.x); s = fmaf(p_.x, q_.x, s); s = fmaf(p_.y, q_.y, s); \
  p_ = cvt2hi(uu.x); q_ = cvt2hi(vv.x); s = fmaf(p_.x, q_.x, s); s = fmaf(p_.y, q_.y, s); \
  p_ = cvt2lo(uu.y); q_ = cvt2lo(vv.y); s = fmaf(p_.x, q_.x, s); s = fmaf(p_.y, q_.y, s); \
  p_ = cvt2hi(uu.y); q_ = cvt2hi(vv.y); s = fmaf(p_.x, q_.x, s); s = fmaf(p_.y, q_.y, s); \
  p_ = cvt2lo(uu.z); q_ = cvt2lo(vv.z); s = fmaf(p_.x, q_.x, s); s = fmaf(p_.y, q_.y, s); \
  p_ = cvt2hi(uu.z); q_ = cvt2hi(vv.z); s = fmaf(p_.x, q_.x, s); s = fmaf(p_.y, q_.y, s); \
  p_ = cvt2lo(uu.w); q_ = cvt2lo(vv.w); s = fmaf(p_.x, q_.x, s); s = fmaf(p_.y, q_.y, s); \
  p_ = cvt2hi(uu.w); q_ = cvt2hi(vv.w); s = fmaf(p_.x, q_.x, s); s = fmaf(p_.y, q_.y, s); }

__global__ __launch_bounds__(256) void loss_fp8(
    const u8* __restrict__ zf8, const int* __restrict__ ep,
    const int* __restrict__ en, int P, float* __restrict__ acc)
{
  __shared__ float red[8];
  const int tid = threadIdx.x;
  const int lane = tid & 63, wib = tid >> 6;
  const int sub = tid & 7;
  const int slot0 = blockIdx.x * 32 + (tid >> 3);
  const int step = gridDim.x * 32;
  float tp = 0.f, tn = 0.f;
  int g = slot0;
  for (; g + step < 2 * P; g += 2 * step) {
    const int gA = g, gB = g + step;
    const int negA = (gA >= P), negB = (gB >= P);
    const int pA = negA ? gA - P : gA, pB = negB ? gB - P : gB;
    const int* iA = negA ? en : ep;
    const int* iB = negB ? en : ep;
    const int naA = iA[pA], nbA = iA[P + pA];
    const int naB = iB[pB], nbB = iB[P + pB];
    const uint4 ra1 = *(const uint4*)(zf8 + (size_t)naA * 128 + sub * 16);
    const uint4 rb1 = *(const uint4*)(zf8 + (size_t)nbA * 128 + sub * 16);
    const uint4 ra2 = *(const uint4*)(zf8 + (size_t)naB * 128 + sub * 16);
    const uint4 rb2 = *(const uint4*)(zf8 + (size_t)nbB * 128 + sub * 16);
    float sA = 0.f, sB = 0.f;
    DOTV(ra1, rb1, sA)
    DOTV(ra2, rb2, sB)
#pragma unroll
    for (int off = 4; off; off >>= 1) {
      sA += __shfl_down(sA, off, 8);
      sB += __shfl_down(sB, off, 8);
    }
    if (sub == 0) {
      const float gA_ = 1.f / (1.f + expf(-sA));
      if (negA) tn += logf(1.f - gA_ + 1e-15f); else tp += logf(gA_ + 1e-15f);
      const float gB_ = 1.f / (1.f + expf(-sB));
      if (negB) tn += logf(1.f - gB_ + 1e-15f); else tp += logf(gB_ + 1e-15f);
    }
  }
  if (g < 2 * P) {
    const int neg = (g >= P);
    const int p = neg ? g - P : g;
    const int* ia = neg ? en : ep;
    const int na = ia[p], nb = ia[P + p];
    const uint4 ra = *(const uint4*)(zf8 + (size_t)na * 128 + sub * 16);
    const uint4 rb = *(const uint4*)(zf8 + (size_t)nb * 128 + sub * 16);
    float s = 0.f;
    DOTV(ra, rb, s)
#pragma unroll
    for (int off = 4; off; off >>= 1) s += __shfl_down(s, off, 8);
    if (sub == 0) {
      const float sig = 1.f / (1.f + expf(-s));
      if (neg) tn += logf(1.f - sig + 1e-15f); else tp += logf(sig + 1e-15f);
    }
  }
  // combine the 8 slot leaders (lanes 0,8,..,56) -> lane 0
  tp += __shfl_down(tp, 32, 64); tn += __shfl_down(tn, 32, 64);
  tp += __shfl_down(tp, 16, 64); tn += __shfl_down(tn, 16, 64);
  tp += __shfl_down(tp, 8, 64);  tn += __shfl_down(tn, 8, 64);
  if (lane == 0) { red[wib] = tp; red[4 + wib] = tn; }
  __syncthreads();
  if (tid == 0) {
    atomicAdd(acc + 0, red[0] + red[1] + red[2] + red[3]);
    atomicAdd(acc + 1, red[4] + red[5] + red[6] + red[7]);
  }
}
#undef DOTV

// ---------------- fused gather2 + final
__global__ void gather2_final(
    const float* __restrict__ t1, const float* __restrict__ t0,
    const int* __restrict__ ptr, const int* __restrict__ cs,
    const float* __restrict__ cw, const float* __restrict__ accs,
    const float* __restrict__ c1, const float* __restrict__ c2,
    float* __restrict__ out, int M, float invP)
{
  const int i = blockIdx.x * blockDim.x + threadIdx.x;
  if (i < M) {
    float a0 = 0.f, a1 = 0.f;
    const int beg = ptr[i], end = ptr[i + 1];
    int p = beg;
    for (; p + 4 <= end; p += 4) {
      const int s0 = cs[p], s1 = cs[p + 1], s2 = cs[p + 2], s3 = cs[p + 3];
      const float w0 = cw[p], w1 = cw[p + 1], w2 = cw[p + 2], w3 = cw[p + 3];
      const float2 v0 = *(const float2*)(t1 + (size_t)s0 * 2);
      const float2 v1 = *(const float2*)(t1 + (size_t)s1 * 2);
      const float2 v2 = *(const float2*)(t1 + (size_t)s2 * 2);
      const float2 v3 = *(const float2*)(t1 + (size_t)s3 * 2);
      a0 = fmaf(w0, v0.x, a0); a1 = fmaf(w0, v0.y, a1);
      a0 = fmaf(w1, v1.x, a0); a1 = fmaf(w1, v1.y, a1);
      a0 = fmaf(w2, v2.x, a0); a1 = fmaf(w2, v2.y, a1);
      a0 = fmaf(w3, v3.x, a0); a1 = fmaf(w3, v3.y, a1);
    }
    for (; p < end; ++p) {
      const int s = cs[p]; const float w = cw[p];
      const float2 v = *(const float2*)(t1 + (size_t)s * 2);
      a0 = fmaf(w, v.x, a0); a1 = fmaf(w, v.y, a1);
    }
    const float2 base = *(const float2*)(t0 + (size_t)i * 2);
    *(float2*)(out + (size_t)i * 2) = make_float2(base.x + a0, base.y + a1);
  }
  if (i == 0) {
    out[2 * M + 0] = -(accs[0] + accs[1]) * invP;
    out[2 * M + 1] = c1[0];
    out[2 * M + 2] = c2[0];
  }
}

extern "C" void kernel_launch(void* const* d_in, const int* in_sizes, int n_in,
                              void* d_out, int out_size, void* d_ws, size_t ws_size,
                              hipStream_t stream)
{
  const float* x   = (const float*)d_in[0];
  const int*   ei  = (const int*)d_in[1];
  const int*   ep  = (const int*)d_in[2];
  const int*   en  = (const int*)d_in[3];
  const float* W1  = (const float*)d_in[4];
  const float* b1  = (const float*)d_in[5];
  const float* W2  = (const float*)d_in[6];
  const float* b2  = (const float*)d_in[7];
  const float* W3  = (const float*)d_in[8];
  const float* b3  = (const float*)d_in[9];
  const float* l1W = (const float*)d_in[10];
  const float* l1b = (const float*)d_in[11];
  const float* l2W = (const float*)d_in[12];
  const float* l2b = (const float*)d_in[13];
  const float* c1  = (const float*)d_in[14];
  const float* c2  = (const float*)d_in[15];
  float* out = (float*)d_out;

  const int M = in_sizes[0] / 128;  // 50000
  const int E = in_sizes[1] / 2;    // 800000
  const int P = in_sizes[2] / 2;    // 400000
  const int* src = ei;
  const int* dst = ei + E;
  const int nb_scan = (M + 255) / 256;

  float* ws = (float*)d_ws;
  size_t o = 0;
  float*    dinv = ws + o;            o += 50176;
  int*      cnt  = (int*)(ws + o);    o += (size_t)M;
  int*      ptr  = (int*)(ws + o);    o += (size_t)M + 8;
  int*      cur  = (int*)(ws + o);    o += (size_t)M;
  int*      bsum = (int*)(ws + o);    o += 256;
  int*      csr_s = (int*)(ws + o);   o += (size_t)E;
  float*    csr_w = ws + o;           o += (size_t)E;
  ushort_t* xb   = (ushort_t*)(ws + o); o += (size_t)M * 64;   // bf16 [M][128]
  u8*       xf8  = (u8*)(ws + o);     o += (size_t)M * 32;     // fp8 [M][128]
  ushort_t* tx0b = (ushort_t*)(ws + o); o += (size_t)M * 64;   // bf16 [M][128]
  ushort_t* W1t  = (ushort_t*)(ws + o); o += 40960;            // [320][256]
  ushort_t* W2t  = (ushort_t*)(ws + o); o += 35840;            // [224][320]
  ushort_t* Wlt  = (ushort_t*)(ws + o); o += 14336;            // [224][128]
  ushort_t* h    = (ushort_t*)(ws + o); o += (size_t)M * 160;  // bf16 [M][320]
  float*    Ar   = ws + o;            o += (size_t)M * 128;    // f32 stride128 -> x1
  u8*       Brh  = (u8*)(ws + o);     o += (size_t)M * 32;     // fp8 [M][128]
  u8*       zf8  = (u8*)(ws + o);     o += (size_t)M * 32;     // fp8 [M][128]
  float*    t0   = ws + o;            o += (size_t)M * 2;
  float*    t1   = ws + o;            o += (size_t)M * 2;
  float*    accs = ws + o;            o += 8;

  hipMemsetAsync(dinv, 0, (size_t)M * 4, stream);
  hipMemsetAsync(cnt,  0, (size_t)M * 4, stream);
  hipMemsetAsync(accs, 0, 2 * 4, stream);
  hipMemsetAsync(Brh,  0, (size_t)M * 128, stream);  // pad cols must decode to 0
  hipMemsetAsync(zf8,  0, (size_t)M * 128, stream);

  // packing (independent, early)
  cvt_x_kernel<<<(M * 32 + 255) / 256, 256, 0, stream>>>(x, xb, xf8, M * 32);
  pack_all<<<(182272 + 255) / 256, 256, 0, stream>>>(W1, W2, l1W, l2W, W1t, W2t, Wlt);

  // CSR build
  deg_count_kernel<<<(E + 255) / 256, 256, 0, stream>>>(src, dst, dinv, cnt, E);
  dinv_kernel<<<(M + 255) / 256, 256, 0, stream>>>(dinv, M);
  scan_local<<<nb_scan, 256, 0, stream>>>(cnt, ptr, bsum, M);
  scan_bsum<<<1, 256, 0, stream>>>(bsum, nb_scan);
  scan_add<<<nb_scan, 256, 0, stream>>>(ptr, bsum, M, E);
  hipMemcpyAsync(cur, ptr, (size_t)M * 4, hipMemcpyDeviceToDevice, stream);
  fill_csr<<<(E + 255) / 256, 256, 0, stream>>>(src, dst, dinv, cur, csr_s, csr_w, E);

  const int gB = (M + 63) / 64;
  const int gE8 = (M * 8 + 255) / 256;

  // conv1
  gather128e<<<gE8, 256, 0, stream>>>(xf8, tx0b, ptr, csr_s, csr_w, M);
  gemm_mfma<0, 320, 256><<<gB, 256, 0, stream>>>(
      xb, tx0b, W1t, b1, nullptr, nullptr, nullptr, nullptr, h, nullptr, nullptr, nullptr, M);

  // conv2 (propagate after GEMM at 100)
  gemm_mfma<1, 224, 320><<<gB, 256, 0, stream>>>(
      h, nullptr, W2t, b2, nullptr, nullptr, nullptr, nullptr, Ar, Brh, nullptr, nullptr, M);
  gather100e_x1<<<gE8, 256, 0, stream>>>(Brh, Ar, ptr, csr_s, csr_w, M);

  // lins + fused w3 (x2 never materialized)
  gemm_mfma<2, 224, 128><<<gB, 256, 0, stream>>>(
      xb, nullptr, Wlt, l1b, l2b, Ar /*x1*/, W3, b3, nullptr, zf8, t0, t1, M);

  // loss
  loss_fp8<<<2048, 256, 0, stream>>>(zf8, ep, en, P, accs);

  // conv3 propagation + final
  gather2_final<<<(M + 255) / 256, 256, 0, stream>>>(t1, t0, ptr, csr_s, csr_w,
                                                     accs, c1, c2, out, M, 1.0f / (float)P);
}